// Round 4
// baseline (836.955 us; speedup 1.0000x reference)
//
#include <hip/hip_runtime.h>
#include <hip/hip_bf16.h>

#define N_NODES 50000
#define N_EDGES 1600000
#define DF 128

// ---------------- CSR build ----------------

// Pass 1: degree count + per-edge local offset (position within its dst bucket).
__global__ __launch_bounds__(256) void p1_kernel(const int* __restrict__ dst,
                                                 int* __restrict__ deg,
                                                 int* __restrict__ loc) {
    int i = blockIdx.x * 256 + threadIdx.x;
    if (i < N_EDGES) {
        int d = dst[i];
        loc[i] = atomicAdd(&deg[d], 1);
    }
}

// block-scan + atomic bump allocator over PADDED degrees (pad to 4 for aligned
// int4 adjacency reads). rstart[n] = start of node n's region (multiple of 4).
__global__ __launch_bounds__(256) void alloc_kernel(const int* __restrict__ degv,
                                                    int* __restrict__ rstart,
                                                    int* __restrict__ counter) {
    __shared__ int buf[256];
    __shared__ int base_s;
    const int tid = threadIdx.x;
    const int i = blockIdx.x * 256 + tid;
    int dv = (i < N_NODES) ? degv[i] : 0;
    int v = (dv + 3) & ~3;  // padded size
    buf[tid] = v;
    __syncthreads();
#pragma unroll
    for (int off = 1; off < 256; off <<= 1) {
        int t = (tid >= off) ? buf[tid - off] : 0;
        __syncthreads();
        buf[tid] += t;
        __syncthreads();
    }
    if (tid == 255) base_s = atomicAdd(counter, buf[255]);
    __syncthreads();
    if (i < N_NODES) rstart[i] = base_s + buf[tid] - v;
}

// Pass 2: atomic-free scatter. Non-temporal store (random 4B writes -> no L2 alloc).
__global__ __launch_bounds__(256) void p2_kernel(const int* __restrict__ src,
                                                 const int* __restrict__ dst,
                                                 const int* __restrict__ loc,
                                                 const int* __restrict__ rstart,
                                                 int* __restrict__ adj) {
    int i = blockIdx.x * 256 + threadIdx.x;
    if (i < N_EDGES) {
        int d = dst[i];
        int pos = rstart[d] + loc[i];
        __builtin_nontemporal_store(src[i], &adj[pos]);
    }
}

// ---------------- aggregation: one wave per node, 8 rows in flight ----------------

__global__ __launch_bounds__(256) void agg_kernel(const float* __restrict__ h,
                                                  const int* __restrict__ rstart,
                                                  const int* __restrict__ degv,
                                                  const int* __restrict__ adj,
                                                  float* __restrict__ neigh) {
    const int wave = threadIdx.x >> 6;
    const int lane = threadIdx.x & 63;
    const int n = blockIdx.x * 4 + wave;
    if (n >= N_NODES) return;
    const int s = rstart[n];   // multiple of 4 -> 16B-aligned int4 reads
    const int d = degv[n];
    const size_t off = (size_t)(lane * 2);
    float ax[8], ay[8];
#pragma unroll
    for (int j = 0; j < 8; j++) { ax[j] = 0.f; ay[j] = 0.f; }
    int i = 0;
    for (; i + 8 <= d; i += 8) {
        int4 a0 = *(const int4*)&adj[s + i];
        int4 a1 = *(const int4*)&adj[s + i + 4];
        float2 v0 = *(const float2*)&h[(size_t)a0.x * DF + off];
        float2 v1 = *(const float2*)&h[(size_t)a0.y * DF + off];
        float2 v2 = *(const float2*)&h[(size_t)a0.z * DF + off];
        float2 v3 = *(const float2*)&h[(size_t)a0.w * DF + off];
        float2 v4 = *(const float2*)&h[(size_t)a1.x * DF + off];
        float2 v5 = *(const float2*)&h[(size_t)a1.y * DF + off];
        float2 v6 = *(const float2*)&h[(size_t)a1.z * DF + off];
        float2 v7 = *(const float2*)&h[(size_t)a1.w * DF + off];
        ax[0] += v0.x; ay[0] += v0.y;
        ax[1] += v1.x; ay[1] += v1.y;
        ax[2] += v2.x; ay[2] += v2.y;
        ax[3] += v3.x; ay[3] += v3.y;
        ax[4] += v4.x; ay[4] += v4.y;
        ax[5] += v5.x; ay[5] += v5.y;
        ax[6] += v6.x; ay[6] += v6.y;
        ax[7] += v7.x; ay[7] += v7.y;
    }
    for (; i < d; i++) {
        int s0 = adj[s + i];
        float2 v = *(const float2*)&h[(size_t)s0 * DF + off];
        ax[0] += v.x; ay[0] += v.y;
    }
    float sx = (ax[0] + ax[1]) + (ax[2] + ax[3]) + ((ax[4] + ax[5]) + (ax[6] + ax[7]));
    float sy = (ay[0] + ay[1]) + (ay[2] + ay[3]) + ((ay[4] + ay[5]) + (ay[6] + ay[7]));
    float inv = 1.0f / (float)(d < 1 ? 1 : d);
    float2 r;
    r.x = sx * inv;
    r.y = sy * inv;
    *(float2*)&neigh[(size_t)n * DF + off] = r;
}

// ---------------- fused GEMM: out = act([h | neigh] @ [Ws; Wn] + b) ----------------
// Block tile 128 nodes x 128 cols, 256 threads, 8x8 register tile.
// X tile LDS-staged with chunk-rotation swizzle; W panel linear.
// Software-pipelined: next K-tile global->reg load overlaps current compute.

__device__ __forceinline__ void gemm_loadX(const float* __restrict__ X, int k0,
                                           int nbase, int tid, float4* r) {
#pragma unroll
    for (int j = 0; j < 4; j++) {
        int sidx = tid + j * 256;          // float4 slot 0..1023
        int node = sidx >> 3;              // 0..127
        int cp = sidx & 7;                 // chunk position
        int c = (cp - ((node >> 3) & 7)) & 7;
        int n = nbase + node;
        if (n > N_NODES - 1) n = N_NODES - 1;
        r[j] = *(const float4*)(X + (size_t)n * DF + k0 + c * 4);
    }
}

__device__ __forceinline__ void gemm_loadW(const float* __restrict__ W, int k0,
                                           int tid, float4* r) {
    const float4* srcv = (const float4*)(W + (size_t)k0 * 128);
#pragma unroll
    for (int j = 0; j < 4; j++) r[j] = srcv[tid + j * 256];
}

template <bool RELU>
__global__ __launch_bounds__(256, 3) void gemm_kernel(const float* __restrict__ hin,
                                                      const float* __restrict__ neigh,
                                                      const float* __restrict__ wS,
                                                      const float* __restrict__ wN,
                                                      const float* __restrict__ bias,
                                                      float* __restrict__ out) {
    __shared__ float Xs[128 * 32];   // [node][32k], 16B chunks rotated by (node>>3)&7
    __shared__ float Ws[32 * 128];   // [k][c], linear

    const int tid = threadIdx.x;
    const int nbase = blockIdx.x * 128;
    const int tn = tid >> 4;   // 0..15 node group
    const int tc = tid & 15;   // 0..15 col group
    const int rot = tn & 7;

    float acc[8][8];
#pragma unroll
    for (int i = 0; i < 8; i++)
#pragma unroll
        for (int j = 0; j < 8; j++) acc[i][j] = 0.f;

    const float* Xsrc[2] = {hin, neigh};
    const float* Wsrc[2] = {wS, wN};

    float4 xr[4], wr[4];
    gemm_loadX(Xsrc[0], 0, nbase, tid, xr);
    gemm_loadW(Wsrc[0], 0, tid, wr);

    // tiles t=0..7: half = t>>2, k0 = (t&3)*32
    for (int t = 0; t < 8; ++t) {
        // store staged regs -> LDS
        {
            float4* dxv = (float4*)Xs;
            float4* dwv = (float4*)Ws;
#pragma unroll
            for (int j = 0; j < 4; j++) {
                dxv[tid + j * 256] = xr[j];
                dwv[tid + j * 256] = wr[j];
            }
        }
        __syncthreads();
        // prefetch next tile into regs (overlaps compute)
        if (t < 7) {
            int t1 = t + 1;
            gemm_loadX(Xsrc[t1 >> 2], (t1 & 3) * 32, nbase, tid, xr);
            gemm_loadW(Wsrc[t1 >> 2], (t1 & 3) * 32, tid, wr);
        }
        // compute current tile
#pragma unroll
        for (int q = 0; q < 8; q++) {
            float4 x[8];
#pragma unroll
            for (int i = 0; i < 8; i++) {
                x[i] = *(const float4*)&Xs[(tn * 8 + i) * 32 + (((q + rot) & 7) * 4)];
            }
            float4 wlo[4], whi[4];
#pragma unroll
            for (int p = 0; p < 4; p++) {
                wlo[p] = *(const float4*)&Ws[(q * 4 + p) * 128 + tc * 4];
                whi[p] = *(const float4*)&Ws[(q * 4 + p) * 128 + 64 + tc * 4];
            }
#pragma unroll
            for (int i = 0; i < 8; i++) {
                acc[i][0] = fmaf(x[i].x, wlo[0].x, fmaf(x[i].y, wlo[1].x, fmaf(x[i].z, wlo[2].x, fmaf(x[i].w, wlo[3].x, acc[i][0]))));
                acc[i][1] = fmaf(x[i].x, wlo[0].y, fmaf(x[i].y, wlo[1].y, fmaf(x[i].z, wlo[2].y, fmaf(x[i].w, wlo[3].y, acc[i][1]))));
                acc[i][2] = fmaf(x[i].x, wlo[0].z, fmaf(x[i].y, wlo[1].z, fmaf(x[i].z, wlo[2].z, fmaf(x[i].w, wlo[3].z, acc[i][2]))));
                acc[i][3] = fmaf(x[i].x, wlo[0].w, fmaf(x[i].y, wlo[1].w, fmaf(x[i].z, wlo[2].w, fmaf(x[i].w, wlo[3].w, acc[i][3]))));
                acc[i][4] = fmaf(x[i].x, whi[0].x, fmaf(x[i].y, whi[1].x, fmaf(x[i].z, whi[2].x, fmaf(x[i].w, whi[3].x, acc[i][4]))));
                acc[i][5] = fmaf(x[i].x, whi[0].y, fmaf(x[i].y, whi[1].y, fmaf(x[i].z, whi[2].y, fmaf(x[i].w, whi[3].y, acc[i][5]))));
                acc[i][6] = fmaf(x[i].x, whi[0].z, fmaf(x[i].y, whi[1].z, fmaf(x[i].z, whi[2].z, fmaf(x[i].w, whi[3].z, acc[i][6]))));
                acc[i][7] = fmaf(x[i].x, whi[0].w, fmaf(x[i].y, whi[1].w, fmaf(x[i].z, whi[2].w, fmaf(x[i].w, whi[3].w, acc[i][7]))));
            }
        }
        __syncthreads();   // protect LDS before next store
    }

    // --- epilogue
    float4 b_lo = *(const float4*)&bias[tc * 4];
    float4 b_hi = *(const float4*)&bias[64 + tc * 4];
#pragma unroll
    for (int i = 0; i < 8; i++) {
        int n = nbase + tn * 8 + i;
        if (n < N_NODES) {
            float4 r0, r1;
            r0.x = acc[i][0] + b_lo.x; r0.y = acc[i][1] + b_lo.y;
            r0.z = acc[i][2] + b_lo.z; r0.w = acc[i][3] + b_lo.w;
            r1.x = acc[i][4] + b_hi.x; r1.y = acc[i][5] + b_hi.y;
            r1.z = acc[i][6] + b_hi.z; r1.w = acc[i][7] + b_hi.w;
            if (RELU) {
                r0.x = fmaxf(r0.x, 0.f); r0.y = fmaxf(r0.y, 0.f);
                r0.z = fmaxf(r0.z, 0.f); r0.w = fmaxf(r0.w, 0.f);
                r1.x = fmaxf(r1.x, 0.f); r1.y = fmaxf(r1.y, 0.f);
                r1.z = fmaxf(r1.z, 0.f); r1.w = fmaxf(r1.w, 0.f);
            }
            *(float4*)&out[(size_t)n * DF + tc * 4] = r0;
            *(float4*)&out[(size_t)n * DF + 64 + tc * 4] = r1;
        }
    }
}

// ---------------- launch ----------------

extern "C" void kernel_launch(void* const* d_in, const int* in_sizes, int n_in,
                              void* d_out, int out_size, void* d_ws, size_t ws_size,
                              hipStream_t stream) {
    const float* feats = (const float*)d_in[0];
    const int* src = (const int*)d_in[1];
    const int* dst = (const int*)d_in[2];
    const float* wS[3] = {(const float*)d_in[3], (const float*)d_in[6], (const float*)d_in[9]};
    const float* wN[3] = {(const float*)d_in[4], (const float*)d_in[7], (const float*)d_in[10]};
    const float* bb[3] = {(const float*)d_in[5], (const float*)d_in[8], (const float*)d_in[11]};
    float* out = (float*)d_out;

    char* p = (char*)d_ws;
    auto alloc = [&](size_t bytes) {
        char* r = p;
        p += (bytes + 255) & ~(size_t)255;
        return r;
    };
    float* neigh = (float*)alloc((size_t)N_NODES * DF * sizeof(float));   // 25.6 MB
    float* hA = (float*)alloc((size_t)N_NODES * DF * sizeof(float));      // 25.6 MB
    int* deg = (int*)alloc((size_t)N_NODES * sizeof(int));
    int* rstart = (int*)alloc((size_t)N_NODES * sizeof(int));
    int* counter = (int*)alloc(sizeof(int));
    int* loc = (int*)alloc((size_t)N_EDGES * sizeof(int));                // 6.4 MB
    int* adj = (int*)alloc((size_t)(N_EDGES + 4 * N_NODES) * sizeof(int)); // 7.2 MB (padded)

    const int EB = (N_EDGES + 255) / 256;
    const int NB = (N_NODES + 255) / 256;

    // CSR build (reused by all 3 layers)
    hipMemsetAsync(deg, 0, (size_t)N_NODES * sizeof(int), stream);
    hipMemsetAsync(counter, 0, sizeof(int), stream);
    p1_kernel<<<EB, 256, 0, stream>>>(dst, deg, loc);
    alloc_kernel<<<NB, 256, 0, stream>>>(deg, rstart, counter);
    p2_kernel<<<EB, 256, 0, stream>>>(src, dst, loc, rstart, adj);

    const int AGG_GRID = (N_NODES + 3) / 4;
    const int GB = (N_NODES + 127) / 128;

    // layer 0: feats -> d_out
    agg_kernel<<<AGG_GRID, 256, 0, stream>>>(feats, rstart, deg, adj, neigh);
    gemm_kernel<true><<<GB, 256, 0, stream>>>(feats, neigh, wS[0], wN[0], bb[0], out);
    // layer 1: d_out -> hA
    agg_kernel<<<AGG_GRID, 256, 0, stream>>>(out, rstart, deg, adj, neigh);
    gemm_kernel<true><<<GB, 256, 0, stream>>>(out, neigh, wS[1], wN[1], bb[1], hA);
    // layer 2: hA -> d_out
    agg_kernel<<<AGG_GRID, 256, 0, stream>>>(hA, rstart, deg, adj, neigh);
    gemm_kernel<false><<<GB, 256, 0, stream>>>(hA, neigh, wS[2], wN[2], bb[2], out);
}

// Round 5
// 582.978 us; speedup vs baseline: 1.4357x; 1.4357x over previous
//
#include <hip/hip_runtime.h>
#include <hip/hip_bf16.h>

#define N_NODES 50000
#define N_EDGES 1600000
#define DF 128

// ---------------- CSR build ----------------

// Pass 1: degree count + per-edge local offset (position within its dst bucket).
__global__ __launch_bounds__(256) void p1_kernel(const int* __restrict__ dst,
                                                 int* __restrict__ deg,
                                                 int* __restrict__ loc) {
    int i = blockIdx.x * 256 + threadIdx.x;
    if (i < N_EDGES) {
        int d = dst[i];
        loc[i] = atomicAdd(&deg[d], 1);
    }
}

// block-scan + atomic bump allocator over PADDED degrees (pad to 4 for aligned
// int4 adjacency reads). rstart[n] = start of node n's region (multiple of 4).
__global__ __launch_bounds__(256) void alloc_kernel(const int* __restrict__ degv,
                                                    int* __restrict__ rstart,
                                                    int* __restrict__ counter) {
    __shared__ int buf[256];
    __shared__ int base_s;
    const int tid = threadIdx.x;
    const int i = blockIdx.x * 256 + tid;
    int dv = (i < N_NODES) ? degv[i] : 0;
    int v = (dv + 3) & ~3;  // padded size
    buf[tid] = v;
    __syncthreads();
#pragma unroll
    for (int off = 1; off < 256; off <<= 1) {
        int t = (tid >= off) ? buf[tid - off] : 0;
        __syncthreads();
        buf[tid] += t;
        __syncthreads();
    }
    if (tid == 255) base_s = atomicAdd(counter, buf[255]);
    __syncthreads();
    if (i < N_NODES) rstart[i] = base_s + buf[tid] - v;
}

// Pass 2: atomic-free scatter. Non-temporal store (random 4B writes -> no L2 alloc).
__global__ __launch_bounds__(256) void p2_kernel(const int* __restrict__ src,
                                                 const int* __restrict__ dst,
                                                 const int* __restrict__ loc,
                                                 const int* __restrict__ rstart,
                                                 int* __restrict__ adj) {
    int i = blockIdx.x * 256 + threadIdx.x;
    if (i < N_EDGES) {
        int d = dst[i];
        int pos = rstart[d] + loc[i];
        __builtin_nontemporal_store(src[i], &adj[pos]);
    }
}

// ---------------- fp32 -> bf16 conversion (RNE), 4 elems/thread ----------------

__global__ __launch_bounds__(256) void conv_kernel(const float* __restrict__ h,
                                                   ushort* __restrict__ hb) {
    int i = blockIdx.x * 256 + threadIdx.x;
    const int total = N_NODES * DF / 4;
    if (i < total) {
        float4 v = ((const float4*)h)[i];
        uint b0 = __float_as_uint(v.x);
        uint b1 = __float_as_uint(v.y);
        uint b2 = __float_as_uint(v.z);
        uint b3 = __float_as_uint(v.w);
        ushort4 o;
        o.x = (ushort)((b0 + 0x7fffu + ((b0 >> 16) & 1u)) >> 16);
        o.y = (ushort)((b1 + 0x7fffu + ((b1 >> 16) & 1u)) >> 16);
        o.z = (ushort)((b2 + 0x7fffu + ((b2 >> 16) & 1u)) >> 16);
        o.w = (ushort)((b3 + 0x7fffu + ((b3 >> 16) & 1u)) >> 16);
        ((ushort4*)hb)[i] = o;
    }
}

// ---------------- aggregation: one wave per node, 8 rows in flight, bf16 gather ----

__global__ __launch_bounds__(256) void agg_kernel(const ushort* __restrict__ hb,
                                                  const int* __restrict__ rstart,
                                                  const int* __restrict__ degv,
                                                  const int* __restrict__ adj,
                                                  float* __restrict__ neigh) {
    const int wave = threadIdx.x >> 6;
    const int lane = threadIdx.x & 63;
    const int n = blockIdx.x * 4 + wave;
    if (n >= N_NODES) return;
    const int s = rstart[n];   // multiple of 4 -> 16B-aligned int4 reads
    const int d = degv[n];
    const int off = lane * 2;  // 2 bf16 per lane = 4B
    float ax[8], ay[8];
#pragma unroll
    for (int j = 0; j < 8; j++) { ax[j] = 0.f; ay[j] = 0.f; }
    int i = 0;
    for (; i + 8 <= d; i += 8) {
        int4 a0 = *(const int4*)&adj[s + i];
        int4 a1 = *(const int4*)&adj[s + i + 4];
        uint u0 = *(const uint*)&hb[(size_t)a0.x * DF + off];
        uint u1 = *(const uint*)&hb[(size_t)a0.y * DF + off];
        uint u2 = *(const uint*)&hb[(size_t)a0.z * DF + off];
        uint u3 = *(const uint*)&hb[(size_t)a0.w * DF + off];
        uint u4 = *(const uint*)&hb[(size_t)a1.x * DF + off];
        uint u5 = *(const uint*)&hb[(size_t)a1.y * DF + off];
        uint u6 = *(const uint*)&hb[(size_t)a1.z * DF + off];
        uint u7 = *(const uint*)&hb[(size_t)a1.w * DF + off];
        ax[0] += __uint_as_float(u0 << 16); ay[0] += __uint_as_float(u0 & 0xffff0000u);
        ax[1] += __uint_as_float(u1 << 16); ay[1] += __uint_as_float(u1 & 0xffff0000u);
        ax[2] += __uint_as_float(u2 << 16); ay[2] += __uint_as_float(u2 & 0xffff0000u);
        ax[3] += __uint_as_float(u3 << 16); ay[3] += __uint_as_float(u3 & 0xffff0000u);
        ax[4] += __uint_as_float(u4 << 16); ay[4] += __uint_as_float(u4 & 0xffff0000u);
        ax[5] += __uint_as_float(u5 << 16); ay[5] += __uint_as_float(u5 & 0xffff0000u);
        ax[6] += __uint_as_float(u6 << 16); ay[6] += __uint_as_float(u6 & 0xffff0000u);
        ax[7] += __uint_as_float(u7 << 16); ay[7] += __uint_as_float(u7 & 0xffff0000u);
    }
    for (; i < d; i++) {
        int s0 = adj[s + i];
        uint u = *(const uint*)&hb[(size_t)s0 * DF + off];
        ax[0] += __uint_as_float(u << 16);
        ay[0] += __uint_as_float(u & 0xffff0000u);
    }
    float sx = (ax[0] + ax[1]) + (ax[2] + ax[3]) + ((ax[4] + ax[5]) + (ax[6] + ax[7]));
    float sy = (ay[0] + ay[1]) + (ay[2] + ay[3]) + ((ay[4] + ay[5]) + (ay[6] + ay[7]));
    float inv = 1.0f / (float)(d < 1 ? 1 : d);
    float2 r;
    r.x = sx * inv;
    r.y = sy * inv;
    *(float2*)&neigh[(size_t)n * DF + off] = r;
}

// ---------------- fused GEMM: out = act([h | neigh] @ [Ws; Wn] + b) ----------------
// Block tile 128 nodes x 128 cols, 256 threads, 8x8 register tile.
// X tile staged in LDS with chunk-rotation swizzle; W panel linear.
// NON-pipelined (no reg prefetch) — R4's prefetch caused scratch spills.

template <bool RELU>
__global__ __launch_bounds__(256, 2) void gemm_kernel(const float* __restrict__ hin,
                                                      const float* __restrict__ neigh,
                                                      const float* __restrict__ wS,
                                                      const float* __restrict__ wN,
                                                      const float* __restrict__ bias,
                                                      float* __restrict__ out) {
    __shared__ float Xs[128 * 32];   // [node][32k], 16B chunks rotated by (node>>3)&7
    __shared__ float Ws[32 * 128];   // [k][c], linear

    const int tid = threadIdx.x;
    const int nbase = blockIdx.x * 128;
    const int tn = tid >> 4;   // 0..15 node group
    const int tc = tid & 15;   // 0..15 col group
    const int rot = tn & 7;

    float acc[8][8];
#pragma unroll
    for (int i = 0; i < 8; i++)
#pragma unroll
        for (int j = 0; j < 8; j++) acc[i][j] = 0.f;

    const float* Xsrc[2] = {hin, neigh};
    const float* Wsrc[2] = {wS, wN};

    for (int half = 0; half < 2; ++half) {
        const float* X = Xsrc[half];
        const float* W = Wsrc[half];
        for (int k0 = 0; k0 < 128; k0 += 32) {
            __syncthreads();  // protect previous iteration's LDS reads
            // --- stage X: chunk c of node m lands at position (c + rot(m)) & 7
            {
                float4* dstv = (float4*)Xs;
#pragma unroll
                for (int j = 0; j < 4; j++) {
                    int sidx = tid + j * 256;          // float4 slot 0..1023
                    int node = sidx >> 3;              // 0..127
                    int cp = sidx & 7;                 // chunk position
                    int c = (cp - ((node >> 3) & 7)) & 7;
                    int n = nbase + node;
                    if (n > N_NODES - 1) n = N_NODES - 1;
                    dstv[sidx] = *(const float4*)(X + (size_t)n * DF + k0 + c * 4);
                }
            }
            // --- stage W: 32x128 contiguous
            {
                const float4* srcv = (const float4*)(W + (size_t)k0 * 128);
                float4* dstv = (float4*)Ws;
#pragma unroll
                for (int j = 0; j < 4; j++) dstv[tid + j * 256] = srcv[tid + j * 256];
            }
            __syncthreads();
            // --- compute
#pragma unroll
            for (int q = 0; q < 8; q++) {
                float4 x[8];
#pragma unroll
                for (int i = 0; i < 8; i++) {
                    x[i] = *(const float4*)&Xs[(tn * 8 + i) * 32 + (((q + rot) & 7) * 4)];
                }
                float4 wlo[4], whi[4];
#pragma unroll
                for (int p = 0; p < 4; p++) {
                    wlo[p] = *(const float4*)&Ws[(q * 4 + p) * 128 + tc * 4];
                    whi[p] = *(const float4*)&Ws[(q * 4 + p) * 128 + 64 + tc * 4];
                }
#pragma unroll
                for (int i = 0; i < 8; i++) {
                    acc[i][0] = fmaf(x[i].x, wlo[0].x, fmaf(x[i].y, wlo[1].x, fmaf(x[i].z, wlo[2].x, fmaf(x[i].w, wlo[3].x, acc[i][0]))));
                    acc[i][1] = fmaf(x[i].x, wlo[0].y, fmaf(x[i].y, wlo[1].y, fmaf(x[i].z, wlo[2].y, fmaf(x[i].w, wlo[3].y, acc[i][1]))));
                    acc[i][2] = fmaf(x[i].x, wlo[0].z, fmaf(x[i].y, wlo[1].z, fmaf(x[i].z, wlo[2].z, fmaf(x[i].w, wlo[3].z, acc[i][2]))));
                    acc[i][3] = fmaf(x[i].x, wlo[0].w, fmaf(x[i].y, wlo[1].w, fmaf(x[i].z, wlo[2].w, fmaf(x[i].w, wlo[3].w, acc[i][3]))));
                    acc[i][4] = fmaf(x[i].x, whi[0].x, fmaf(x[i].y, whi[1].x, fmaf(x[i].z, whi[2].x, fmaf(x[i].w, whi[3].x, acc[i][4]))));
                    acc[i][5] = fmaf(x[i].x, whi[0].y, fmaf(x[i].y, whi[1].y, fmaf(x[i].z, whi[2].y, fmaf(x[i].w, whi[3].y, acc[i][5]))));
                    acc[i][6] = fmaf(x[i].x, whi[0].z, fmaf(x[i].y, whi[1].z, fmaf(x[i].z, whi[2].z, fmaf(x[i].w, whi[3].z, acc[i][6]))));
                    acc[i][7] = fmaf(x[i].x, whi[0].w, fmaf(x[i].y, whi[1].w, fmaf(x[i].z, whi[2].w, fmaf(x[i].w, whi[3].w, acc[i][7]))));
                }
            }
        }
    }

    // --- epilogue
    float4 b_lo = *(const float4*)&bias[tc * 4];
    float4 b_hi = *(const float4*)&bias[64 + tc * 4];
#pragma unroll
    for (int i = 0; i < 8; i++) {
        int n = nbase + tn * 8 + i;
        if (n < N_NODES) {
            float4 r0, r1;
            r0.x = acc[i][0] + b_lo.x; r0.y = acc[i][1] + b_lo.y;
            r0.z = acc[i][2] + b_lo.z; r0.w = acc[i][3] + b_lo.w;
            r1.x = acc[i][4] + b_hi.x; r1.y = acc[i][5] + b_hi.y;
            r1.z = acc[i][6] + b_hi.z; r1.w = acc[i][7] + b_hi.w;
            if (RELU) {
                r0.x = fmaxf(r0.x, 0.f); r0.y = fmaxf(r0.y, 0.f);
                r0.z = fmaxf(r0.z, 0.f); r0.w = fmaxf(r0.w, 0.f);
                r1.x = fmaxf(r1.x, 0.f); r1.y = fmaxf(r1.y, 0.f);
                r1.z = fmaxf(r1.z, 0.f); r1.w = fmaxf(r1.w, 0.f);
            }
            *(float4*)&out[(size_t)n * DF + tc * 4] = r0;
            *(float4*)&out[(size_t)n * DF + 64 + tc * 4] = r1;
        }
    }
}

// ---------------- launch ----------------

extern "C" void kernel_launch(void* const* d_in, const int* in_sizes, int n_in,
                              void* d_out, int out_size, void* d_ws, size_t ws_size,
                              hipStream_t stream) {
    const float* feats = (const float*)d_in[0];
    const int* src = (const int*)d_in[1];
    const int* dst = (const int*)d_in[2];
    const float* wS[3] = {(const float*)d_in[3], (const float*)d_in[6], (const float*)d_in[9]};
    const float* wN[3] = {(const float*)d_in[4], (const float*)d_in[7], (const float*)d_in[10]};
    const float* bb[3] = {(const float*)d_in[5], (const float*)d_in[8], (const float*)d_in[11]};
    float* out = (float*)d_out;

    char* p = (char*)d_ws;
    auto alloc = [&](size_t bytes) {
        char* r = p;
        p += (bytes + 255) & ~(size_t)255;
        return r;
    };
    float* neigh = (float*)alloc((size_t)N_NODES * DF * sizeof(float));    // 25.6 MB
    float* hA = (float*)alloc((size_t)N_NODES * DF * sizeof(float));       // 25.6 MB
    ushort* hb = (ushort*)alloc((size_t)N_NODES * DF * sizeof(ushort));    // 12.8 MB
    int* deg = (int*)alloc((size_t)N_NODES * sizeof(int));
    int* rstart = (int*)alloc((size_t)N_NODES * sizeof(int));
    int* counter = (int*)alloc(sizeof(int));
    int* loc = (int*)alloc((size_t)N_EDGES * sizeof(int));                 // 6.4 MB
    int* adj = (int*)alloc((size_t)(N_EDGES + 4 * N_NODES) * sizeof(int)); // 7.2 MB (padded)

    const int EB = (N_EDGES + 255) / 256;
    const int NB = (N_NODES + 255) / 256;
    const int CB = (N_NODES * DF / 4 + 255) / 256;

    // CSR build (reused by all 3 layers)
    hipMemsetAsync(deg, 0, (size_t)N_NODES * sizeof(int), stream);
    hipMemsetAsync(counter, 0, sizeof(int), stream);
    p1_kernel<<<EB, 256, 0, stream>>>(dst, deg, loc);
    alloc_kernel<<<NB, 256, 0, stream>>>(deg, rstart, counter);
    p2_kernel<<<EB, 256, 0, stream>>>(src, dst, loc, rstart, adj);

    const int AGG_GRID = (N_NODES + 3) / 4;
    const int GB = (N_NODES + 127) / 128;

    // layer 0: feats -> d_out
    conv_kernel<<<CB, 256, 0, stream>>>(feats, hb);
    agg_kernel<<<AGG_GRID, 256, 0, stream>>>(hb, rstart, deg, adj, neigh);
    gemm_kernel<true><<<GB, 256, 0, stream>>>(feats, neigh, wS[0], wN[0], bb[0], out);
    // layer 1: d_out -> hA
    conv_kernel<<<CB, 256, 0, stream>>>(out, hb);
    agg_kernel<<<AGG_GRID, 256, 0, stream>>>(hb, rstart, deg, adj, neigh);
    gemm_kernel<true><<<GB, 256, 0, stream>>>(out, neigh, wS[1], wN[1], bb[1], hA);
    // layer 2: hA -> d_out
    conv_kernel<<<CB, 256, 0, stream>>>(hA, hb);
    agg_kernel<<<AGG_GRID, 256, 0, stream>>>(hb, rstart, deg, adj, neigh);
    gemm_kernel<false><<<GB, 256, 0, stream>>>(hA, neigh, wS[2], wN[2], bb[2], out);
}

// Round 7
// 559.766 us; speedup vs baseline: 1.4952x; 1.0415x over previous
//
#include <hip/hip_runtime.h>
#include <hip/hip_bf16.h>

#define N_NODES 50000
#define N_EDGES 1600000
#define DF 128
#define NC 8   // atomic-spread copies (~XCDs)

// ---------------- CSR build ----------------

// Pass 1: degree count into NC private histograms + per-edge local offset.
__global__ __launch_bounds__(256) void p1_kernel(const int* __restrict__ dst,
                                                 int* __restrict__ deg_c,
                                                 int* __restrict__ loc) {
    int i = blockIdx.x * 256 + threadIdx.x;
    int c = blockIdx.x & (NC - 1);
    if (i < N_EDGES) {
        int d = dst[i];
        loc[i] = atomicAdd(&deg_c[c * N_NODES + d], 1);
    }
}

// Sum NC copies, pad to 4, block-scan + atomic bump allocator.
// Emits deg (true degree), rstart (region start), cstart[c][n] (per-copy start).
__global__ __launch_bounds__(256) void alloc_kernel(const int* __restrict__ deg_c,
                                                    int* __restrict__ deg,
                                                    int* __restrict__ rstart,
                                                    int* __restrict__ cstart,
                                                    int* __restrict__ counter) {
    __shared__ int buf[256];
    __shared__ int base_s;
    const int tid = threadIdx.x;
    const int i = blockIdx.x * 256 + tid;
    int pc[NC];
    int t = 0;
    if (i < N_NODES) {
#pragma unroll
        for (int c = 0; c < NC; c++) {
            pc[c] = t;
            t += deg_c[c * N_NODES + i];
        }
        deg[i] = t;
    }
    int v = (t + 3) & ~3;  // padded region size
    buf[tid] = v;
    __syncthreads();
#pragma unroll
    for (int off = 1; off < 256; off <<= 1) {
        int x = (tid >= off) ? buf[tid - off] : 0;
        __syncthreads();
        buf[tid] += x;
        __syncthreads();
    }
    if (tid == 255) base_s = atomicAdd(counter, buf[255]);
    __syncthreads();
    if (i < N_NODES) {
        int rs = base_s + buf[tid] - v;
        rstart[i] = rs;
#pragma unroll
        for (int c = 0; c < NC; c++) cstart[c * N_NODES + i] = rs + pc[c];
    }
}

// Pass 2: atomic-free scatter (same block->copy mapping as p1). NT store.
__global__ __launch_bounds__(256) void p2_kernel(const int* __restrict__ src,
                                                 const int* __restrict__ dst,
                                                 const int* __restrict__ loc,
                                                 const int* __restrict__ cstart,
                                                 int* __restrict__ adj) {
    int i = blockIdx.x * 256 + threadIdx.x;
    int c = blockIdx.x & (NC - 1);
    if (i < N_EDGES) {
        int d = dst[i];
        int pos = cstart[c * N_NODES + d] + loc[i];
        __builtin_nontemporal_store(src[i], &adj[pos]);
    }
}

// ---------------- fp32 -> bf16 conversion (RNE), 4 elems/thread ----------------

__global__ __launch_bounds__(256) void conv_kernel(const float* __restrict__ h,
                                                   ushort* __restrict__ hb) {
    int i = blockIdx.x * 256 + threadIdx.x;
    const int total = N_NODES * DF / 4;
    if (i < total) {
        float4 v = ((const float4*)h)[i];
        uint b0 = __float_as_uint(v.x);
        uint b1 = __float_as_uint(v.y);
        uint b2 = __float_as_uint(v.z);
        uint b3 = __float_as_uint(v.w);
        ushort4 o;
        o.x = (ushort)((b0 + 0x7fffu + ((b0 >> 16) & 1u)) >> 16);
        o.y = (ushort)((b1 + 0x7fffu + ((b1 >> 16) & 1u)) >> 16);
        o.z = (ushort)((b2 + 0x7fffu + ((b2 >> 16) & 1u)) >> 16);
        o.w = (ushort)((b3 + 0x7fffu + ((b3 >> 16) & 1u)) >> 16);
        ((ushort4*)hb)[i] = o;
    }
}

// ---------------- aggregation: one wave per node, 8 rows in flight, bf16 gather ----

__global__ __launch_bounds__(256) void agg_kernel(const ushort* __restrict__ hb,
                                                  const int* __restrict__ rstart,
                                                  const int* __restrict__ degv,
                                                  const int* __restrict__ adj,
                                                  float* __restrict__ neigh) {
    const int wave = threadIdx.x >> 6;
    const int lane = threadIdx.x & 63;
    const int n = blockIdx.x * 4 + wave;
    if (n >= N_NODES) return;
    const int s = rstart[n];   // multiple of 4 -> 16B-aligned int4 reads
    const int d = degv[n];
    const int off = lane * 2;  // 2 bf16 per lane = 4B
    float ax[8], ay[8];
#pragma unroll
    for (int j = 0; j < 8; j++) { ax[j] = 0.f; ay[j] = 0.f; }
    int i = 0;
    for (; i + 8 <= d; i += 8) {
        int4 a0 = *(const int4*)&adj[s + i];
        int4 a1 = *(const int4*)&adj[s + i + 4];
        uint u0 = *(const uint*)&hb[(size_t)a0.x * DF + off];
        uint u1 = *(const uint*)&hb[(size_t)a0.y * DF + off];
        uint u2 = *(const uint*)&hb[(size_t)a0.z * DF + off];
        uint u3 = *(const uint*)&hb[(size_t)a0.w * DF + off];
        uint u4 = *(const uint*)&hb[(size_t)a1.x * DF + off];
        uint u5 = *(const uint*)&hb[(size_t)a1.y * DF + off];
        uint u6 = *(const uint*)&hb[(size_t)a1.z * DF + off];
        uint u7 = *(const uint*)&hb[(size_t)a1.w * DF + off];
        ax[0] += __uint_as_float(u0 << 16); ay[0] += __uint_as_float(u0 & 0xffff0000u);
        ax[1] += __uint_as_float(u1 << 16); ay[1] += __uint_as_float(u1 & 0xffff0000u);
        ax[2] += __uint_as_float(u2 << 16); ay[2] += __uint_as_float(u2 & 0xffff0000u);
        ax[3] += __uint_as_float(u3 << 16); ay[3] += __uint_as_float(u3 & 0xffff0000u);
        ax[4] += __uint_as_float(u4 << 16); ay[4] += __uint_as_float(u4 & 0xffff0000u);
        ax[5] += __uint_as_float(u5 << 16); ay[5] += __uint_as_float(u5 & 0xffff0000u);
        ax[6] += __uint_as_float(u6 << 16); ay[6] += __uint_as_float(u6 & 0xffff0000u);
        ax[7] += __uint_as_float(u7 << 16); ay[7] += __uint_as_float(u7 & 0xffff0000u);
    }
    for (; i < d; i++) {
        int s0 = adj[s + i];
        uint u = *(const uint*)&hb[(size_t)s0 * DF + off];
        ax[0] += __uint_as_float(u << 16);
        ay[0] += __uint_as_float(u & 0xffff0000u);
    }
    float sx = (ax[0] + ax[1]) + (ax[2] + ax[3]) + ((ax[4] + ax[5]) + (ax[6] + ax[7]));
    float sy = (ay[0] + ay[1]) + (ay[2] + ay[3]) + ((ay[4] + ay[5]) + (ay[6] + ay[7]));
    float inv = 1.0f / (float)(d < 1 ? 1 : d);
    float2 r;
    r.x = sx * inv;
    r.y = sy * inv;
    *(float2*)&neigh[(size_t)n * DF + off] = r;
}

// ---------------- fused GEMM: out = act([h | neigh] @ [Ws; Wn] + b) ----------------
// Block tile 128 nodes x 128 cols, 256 threads, 8x8 register tile.
// X tile staged in LDS with chunk-rotation swizzle; W panel linear.
// Optionally writes a bf16 copy of the output (fuses next layer's conv pass).

template <bool RELU, bool WRITE_BF16>
__global__ __launch_bounds__(256, 2) void gemm_kernel(const float* __restrict__ hin,
                                                      const float* __restrict__ neigh,
                                                      const float* __restrict__ wS,
                                                      const float* __restrict__ wN,
                                                      const float* __restrict__ bias,
                                                      float* __restrict__ out,
                                                      ushort* __restrict__ hbout) {
    __shared__ float Xs[128 * 32];   // [node][32k], 16B chunks rotated by (node>>3)&7
    __shared__ float Ws[32 * 128];   // [k][c], linear

    const int tid = threadIdx.x;
    const int nbase = blockIdx.x * 128;
    const int tn = tid >> 4;   // 0..15 node group
    const int tc = tid & 15;   // 0..15 col group
    const int rot = tn & 7;

    float acc[8][8];
#pragma unroll
    for (int i = 0; i < 8; i++)
#pragma unroll
        for (int j = 0; j < 8; j++) acc[i][j] = 0.f;

    const float* Xsrc[2] = {hin, neigh};
    const float* Wsrc[2] = {wS, wN};

    for (int half = 0; half < 2; ++half) {
        const float* X = Xsrc[half];
        const float* W = Wsrc[half];
        for (int k0 = 0; k0 < 128; k0 += 32) {
            __syncthreads();  // protect previous iteration's LDS reads
            // --- stage X: chunk c of node m lands at position (c + rot(m)) & 7
            {
                float4* dstv = (float4*)Xs;
#pragma unroll
                for (int j = 0; j < 4; j++) {
                    int sidx = tid + j * 256;          // float4 slot 0..1023
                    int node = sidx >> 3;              // 0..127
                    int cp = sidx & 7;                 // chunk position
                    int c = (cp - ((node >> 3) & 7)) & 7;
                    int n = nbase + node;
                    if (n > N_NODES - 1) n = N_NODES - 1;
                    dstv[sidx] = *(const float4*)(X + (size_t)n * DF + k0 + c * 4);
                }
            }
            // --- stage W: 32x128 contiguous
            {
                const float4* srcv = (const float4*)(W + (size_t)k0 * 128);
                float4* dstv = (float4*)Ws;
#pragma unroll
                for (int j = 0; j < 4; j++) dstv[tid + j * 256] = srcv[tid + j * 256];
            }
            __syncthreads();
            // --- compute
#pragma unroll
            for (int q = 0; q < 8; q++) {
                float4 x[8];
#pragma unroll
                for (int i = 0; i < 8; i++) {
                    x[i] = *(const float4*)&Xs[(tn * 8 + i) * 32 + (((q + rot) & 7) * 4)];
                }
                float4 wlo[4], whi[4];
#pragma unroll
                for (int p = 0; p < 4; p++) {
                    wlo[p] = *(const float4*)&Ws[(q * 4 + p) * 128 + tc * 4];
                    whi[p] = *(const float4*)&Ws[(q * 4 + p) * 128 + 64 + tc * 4];
                }
#pragma unroll
                for (int i = 0; i < 8; i++) {
                    acc[i][0] = fmaf(x[i].x, wlo[0].x, fmaf(x[i].y, wlo[1].x, fmaf(x[i].z, wlo[2].x, fmaf(x[i].w, wlo[3].x, acc[i][0]))));
                    acc[i][1] = fmaf(x[i].x, wlo[0].y, fmaf(x[i].y, wlo[1].y, fmaf(x[i].z, wlo[2].y, fmaf(x[i].w, wlo[3].y, acc[i][1]))));
                    acc[i][2] = fmaf(x[i].x, wlo[0].z, fmaf(x[i].y, wlo[1].z, fmaf(x[i].z, wlo[2].z, fmaf(x[i].w, wlo[3].z, acc[i][2]))));
                    acc[i][3] = fmaf(x[i].x, wlo[0].w, fmaf(x[i].y, wlo[1].w, fmaf(x[i].z, wlo[2].w, fmaf(x[i].w, wlo[3].w, acc[i][3]))));
                    acc[i][4] = fmaf(x[i].x, whi[0].x, fmaf(x[i].y, whi[1].x, fmaf(x[i].z, whi[2].x, fmaf(x[i].w, whi[3].x, acc[i][4]))));
                    acc[i][5] = fmaf(x[i].x, whi[0].y, fmaf(x[i].y, whi[1].y, fmaf(x[i].z, whi[2].y, fmaf(x[i].w, whi[3].y, acc[i][5]))));
                    acc[i][6] = fmaf(x[i].x, whi[0].z, fmaf(x[i].y, whi[1].z, fmaf(x[i].z, whi[2].z, fmaf(x[i].w, whi[3].z, acc[i][6]))));
                    acc[i][7] = fmaf(x[i].x, whi[0].w, fmaf(x[i].y, whi[1].w, fmaf(x[i].z, whi[2].w, fmaf(x[i].w, whi[3].w, acc[i][7]))));
                }
            }
        }
    }

    // --- epilogue
    float4 b_lo = *(const float4*)&bias[tc * 4];
    float4 b_hi = *(const float4*)&bias[64 + tc * 4];
#pragma unroll
    for (int i = 0; i < 8; i++) {
        int n = nbase + tn * 8 + i;
        if (n < N_NODES) {
            float4 r0, r1;
            r0.x = acc[i][0] + b_lo.x; r0.y = acc[i][1] + b_lo.y;
            r0.z = acc[i][2] + b_lo.z; r0.w = acc[i][3] + b_lo.w;
            r1.x = acc[i][4] + b_hi.x; r1.y = acc[i][5] + b_hi.y;
            r1.z = acc[i][6] + b_hi.z; r1.w = acc[i][7] + b_hi.w;
            if (RELU) {
                r0.x = fmaxf(r0.x, 0.f); r0.y = fmaxf(r0.y, 0.f);
                r0.z = fmaxf(r0.z, 0.f); r0.w = fmaxf(r0.w, 0.f);
                r1.x = fmaxf(r1.x, 0.f); r1.y = fmaxf(r1.y, 0.f);
                r1.z = fmaxf(r1.z, 0.f); r1.w = fmaxf(r1.w, 0.f);
            }
            *(float4*)&out[(size_t)n * DF + tc * 4] = r0;
            *(float4*)&out[(size_t)n * DF + 64 + tc * 4] = r1;
            if (WRITE_BF16) {
                uint c0 = __float_as_uint(r0.x), c1 = __float_as_uint(r0.y);
                uint c2 = __float_as_uint(r0.z), c3 = __float_as_uint(r0.w);
                uint c4 = __float_as_uint(r1.x), c5 = __float_as_uint(r1.y);
                uint c6 = __float_as_uint(r1.z), c7 = __float_as_uint(r1.w);
                ushort4 o0, o1;
                o0.x = (ushort)((c0 + 0x7fffu + ((c0 >> 16) & 1u)) >> 16);
                o0.y = (ushort)((c1 + 0x7fffu + ((c1 >> 16) & 1u)) >> 16);
                o0.z = (ushort)((c2 + 0x7fffu + ((c2 >> 16) & 1u)) >> 16);
                o0.w = (ushort)((c3 + 0x7fffu + ((c3 >> 16) & 1u)) >> 16);
                o1.x = (ushort)((c4 + 0x7fffu + ((c4 >> 16) & 1u)) >> 16);
                o1.y = (ushort)((c5 + 0x7fffu + ((c5 >> 16) & 1u)) >> 16);
                o1.z = (ushort)((c6 + 0x7fffu + ((c6 >> 16) & 1u)) >> 16);
                o1.w = (ushort)((c7 + 0x7fffu + ((c7 >> 16) & 1u)) >> 16);
                *(ushort4*)&hbout[(size_t)n * DF + tc * 4] = o0;
                *(ushort4*)&hbout[(size_t)n * DF + 64 + tc * 4] = o1;
            }
        }
    }
}

// ---------------- launch ----------------

extern "C" void kernel_launch(void* const* d_in, const int* in_sizes, int n_in,
                              void* d_out, int out_size, void* d_ws, size_t ws_size,
                              hipStream_t stream) {
    const float* feats = (const float*)d_in[0];
    const int* src = (const int*)d_in[1];
    const int* dst = (const int*)d_in[2];
    const float* wS[3] = {(const float*)d_in[3], (const float*)d_in[6], (const float*)d_in[9]};
    const float* wN[3] = {(const float*)d_in[4], (const float*)d_in[7], (const float*)d_in[10]};
    const float* bb[3] = {(const float*)d_in[5], (const float*)d_in[8], (const float*)d_in[11]};
    float* out = (float*)d_out;

    char* p = (char*)d_ws;
    auto alloc = [&](size_t bytes) {
        char* r = p;
        p += (bytes + 255) & ~(size_t)255;
        return r;
    };
    float* neigh = (float*)alloc((size_t)N_NODES * DF * sizeof(float));    // 25.6 MB
    float* hA = (float*)alloc((size_t)N_NODES * DF * sizeof(float));       // 25.6 MB
    ushort* hb = (ushort*)alloc((size_t)N_NODES * DF * sizeof(ushort));    // 12.8 MB
    int* deg_c = (int*)alloc((size_t)NC * N_NODES * sizeof(int));          // 1.6 MB
    int* cstart = (int*)alloc((size_t)NC * N_NODES * sizeof(int));         // 1.6 MB
    int* deg = (int*)alloc((size_t)N_NODES * sizeof(int));
    int* rstart = (int*)alloc((size_t)N_NODES * sizeof(int));
    int* counter = (int*)alloc(sizeof(int));
    int* loc = (int*)alloc((size_t)N_EDGES * sizeof(int));                 // 6.4 MB
    int* adj = (int*)alloc((size_t)(N_EDGES + 4 * N_NODES) * sizeof(int)); // 7.2 MB (padded)

    const int EB = (N_EDGES + 255) / 256;
    const int NB = (N_NODES + 255) / 256;
    const int CB = (N_NODES * DF / 4 + 255) / 256;

    // CSR build (reused by all 3 layers)
    hipMemsetAsync(deg_c, 0, (size_t)NC * N_NODES * sizeof(int), stream);
    hipMemsetAsync(counter, 0, sizeof(int), stream);
    p1_kernel<<<EB, 256, 0, stream>>>(dst, deg_c, loc);
    alloc_kernel<<<NB, 256, 0, stream>>>(deg_c, deg, rstart, cstart, counter);
    p2_kernel<<<EB, 256, 0, stream>>>(src, dst, loc, cstart, adj);

    const int AGG_GRID = (N_NODES + 3) / 4;
    const int GB = (N_NODES + 127) / 128;

    // layer 0: feats -> d_out (+ hb for layer 1)
    conv_kernel<<<CB, 256, 0, stream>>>(feats, hb);
    agg_kernel<<<AGG_GRID, 256, 0, stream>>>(hb, rstart, deg, adj, neigh);
    gemm_kernel<true, true><<<GB, 256, 0, stream>>>(feats, neigh, wS[0], wN[0], bb[0], out, hb);
    // layer 1: d_out -> hA (+ hb for layer 2)
    agg_kernel<<<AGG_GRID, 256, 0, stream>>>(hb, rstart, deg, adj, neigh);
    gemm_kernel<true, true><<<GB, 256, 0, stream>>>(out, neigh, wS[1], wN[1], bb[1], hA, hb);
    // layer 2: hA -> d_out
    agg_kernel<<<AGG_GRID, 256, 0, stream>>>(hb, rstart, deg, adj, neigh);
    gemm_kernel<false, false><<<GB, 256, 0, stream>>>(hA, neigh, wS[2], wN[2], bb[2], out, nullptr);
}

// Round 8
// 434.990 us; speedup vs baseline: 1.9241x; 1.2868x over previous
//
#include <hip/hip_runtime.h>
#include <hip/hip_bf16.h>

#define N_NODES 50000
#define N_EDGES 1600000
#define DF 128
#define NC 8   // atomic-spread copies (~XCDs)

typedef __attribute__((ext_vector_type(8))) short short8v;
typedef __attribute__((ext_vector_type(4))) float float4v;

__device__ __forceinline__ ushort bf16rne(float f) {
    uint u = __float_as_uint(f);
    return (ushort)((u + 0x7fffu + ((u >> 16) & 1u)) >> 16);
}

// ---------------- CSR build ----------------

__global__ __launch_bounds__(256) void p1_kernel(const int* __restrict__ dst,
                                                 int* __restrict__ deg_c,
                                                 int* __restrict__ loc) {
    int i = blockIdx.x * 256 + threadIdx.x;
    int c = blockIdx.x & (NC - 1);
    if (i < N_EDGES) {
        int d = dst[i];
        loc[i] = atomicAdd(&deg_c[c * N_NODES + d], 1);
    }
}

__global__ __launch_bounds__(256) void alloc_kernel(const int* __restrict__ deg_c,
                                                    int* __restrict__ deg,
                                                    int* __restrict__ rstart,
                                                    int* __restrict__ cstart,
                                                    int* __restrict__ counter) {
    __shared__ int buf[256];
    __shared__ int base_s;
    const int tid = threadIdx.x;
    const int i = blockIdx.x * 256 + tid;
    int pc[NC];
    int t = 0;
    if (i < N_NODES) {
#pragma unroll
        for (int c = 0; c < NC; c++) {
            pc[c] = t;
            t += deg_c[c * N_NODES + i];
        }
        deg[i] = t;
    }
    int v = (t + 3) & ~3;
    buf[tid] = v;
    __syncthreads();
#pragma unroll
    for (int off = 1; off < 256; off <<= 1) {
        int x = (tid >= off) ? buf[tid - off] : 0;
        __syncthreads();
        buf[tid] += x;
        __syncthreads();
    }
    if (tid == 255) base_s = atomicAdd(counter, buf[255]);
    __syncthreads();
    if (i < N_NODES) {
        int rs = base_s + buf[tid] - v;
        rstart[i] = rs;
#pragma unroll
        for (int c = 0; c < NC; c++) cstart[c * N_NODES + i] = rs + pc[c];
    }
}

__global__ __launch_bounds__(256) void p2_kernel(const int* __restrict__ src,
                                                 const int* __restrict__ dst,
                                                 const int* __restrict__ loc,
                                                 const int* __restrict__ cstart,
                                                 int* __restrict__ adj) {
    int i = blockIdx.x * 256 + threadIdx.x;
    int c = blockIdx.x & (NC - 1);
    if (i < N_EDGES) {
        int d = dst[i];
        int pos = cstart[c * N_NODES + d] + loc[i];
        __builtin_nontemporal_store(src[i], &adj[pos]);
    }
}

// ---------------- fp32 -> bf16 conversion (RNE), 4 elems/thread ----------------

__global__ __launch_bounds__(256) void conv_kernel(const float* __restrict__ h,
                                                   ushort* __restrict__ hb) {
    int i = blockIdx.x * 256 + threadIdx.x;
    const int total = N_NODES * DF / 4;
    if (i < total) {
        float4 v = ((const float4*)h)[i];
        ushort4 o;
        o.x = bf16rne(v.x); o.y = bf16rne(v.y);
        o.z = bf16rne(v.z); o.w = bf16rne(v.w);
        ((ushort4*)hb)[i] = o;
    }
}

// ---------------- weight prep: Wt[col][k] bf16, k = [Ws rows | Wn rows] ----------

__global__ __launch_bounds__(256) void wprep_kernel(const float* __restrict__ wS,
                                                    const float* __restrict__ wN,
                                                    ushort* __restrict__ Wt) {
    int idx = blockIdx.x * 256 + threadIdx.x;  // 128*256 total
    if (idx < 128 * 256) {
        int c = idx >> 8;
        int k = idx & 255;
        float v = (k < 128) ? wS[k * 128 + c] : wN[(k - 128) * 128 + c];
        Wt[c * 256 + k] = bf16rne(v);
    }
}

// ---------------- aggregation: one wave per node, 8 rows in flight, bf16 -> bf16 --

__global__ __launch_bounds__(256) void agg_kernel(const ushort* __restrict__ hb,
                                                  const int* __restrict__ rstart,
                                                  const int* __restrict__ degv,
                                                  const int* __restrict__ adj,
                                                  ushort* __restrict__ neighb) {
    const int wave = threadIdx.x >> 6;
    const int lane = threadIdx.x & 63;
    const int n = blockIdx.x * 4 + wave;
    if (n >= N_NODES) return;
    const int s = rstart[n];
    const int d = degv[n];
    const int off = lane * 2;
    float ax[8], ay[8];
#pragma unroll
    for (int j = 0; j < 8; j++) { ax[j] = 0.f; ay[j] = 0.f; }
    int i = 0;
    for (; i + 8 <= d; i += 8) {
        int4 a0 = *(const int4*)&adj[s + i];
        int4 a1 = *(const int4*)&adj[s + i + 4];
        uint u0 = *(const uint*)&hb[(size_t)a0.x * DF + off];
        uint u1 = *(const uint*)&hb[(size_t)a0.y * DF + off];
        uint u2 = *(const uint*)&hb[(size_t)a0.z * DF + off];
        uint u3 = *(const uint*)&hb[(size_t)a0.w * DF + off];
        uint u4 = *(const uint*)&hb[(size_t)a1.x * DF + off];
        uint u5 = *(const uint*)&hb[(size_t)a1.y * DF + off];
        uint u6 = *(const uint*)&hb[(size_t)a1.z * DF + off];
        uint u7 = *(const uint*)&hb[(size_t)a1.w * DF + off];
        ax[0] += __uint_as_float(u0 << 16); ay[0] += __uint_as_float(u0 & 0xffff0000u);
        ax[1] += __uint_as_float(u1 << 16); ay[1] += __uint_as_float(u1 & 0xffff0000u);
        ax[2] += __uint_as_float(u2 << 16); ay[2] += __uint_as_float(u2 & 0xffff0000u);
        ax[3] += __uint_as_float(u3 << 16); ay[3] += __uint_as_float(u3 & 0xffff0000u);
        ax[4] += __uint_as_float(u4 << 16); ay[4] += __uint_as_float(u4 & 0xffff0000u);
        ax[5] += __uint_as_float(u5 << 16); ay[5] += __uint_as_float(u5 & 0xffff0000u);
        ax[6] += __uint_as_float(u6 << 16); ay[6] += __uint_as_float(u6 & 0xffff0000u);
        ax[7] += __uint_as_float(u7 << 16); ay[7] += __uint_as_float(u7 & 0xffff0000u);
    }
    for (; i < d; i++) {
        int s0 = adj[s + i];
        uint u = *(const uint*)&hb[(size_t)s0 * DF + off];
        ax[0] += __uint_as_float(u << 16);
        ay[0] += __uint_as_float(u & 0xffff0000u);
    }
    float sx = (ax[0] + ax[1]) + (ax[2] + ax[3]) + ((ax[4] + ax[5]) + (ax[6] + ax[7]));
    float sy = (ay[0] + ay[1]) + (ay[2] + ay[3]) + ((ay[4] + ay[5]) + (ay[6] + ay[7]));
    float inv = 1.0f / (float)(d < 1 ? 1 : d);
    ushort2 o;
    o.x = bf16rne(sx * inv);
    o.y = bf16rne(sy * inv);
    *(ushort2*)&neighb[(size_t)n * DF + off] = o;
}

// ---------------- MFMA GEMM: out = act([hb | neighb] @ Wt^T + b) -----------------
// 128 nodes x 128 cols per block, 4 waves (2x2), each wave 64x64 via 4x4 16x16x32
// MFMA fragments. A,B tiles in LDS [128][40] bf16 (pad->2-way conflicts = free).
// A: lane holds row=l&15, k=(l>>4)*8+j (8 contiguous bf16).
// B: from Wt[col][k] (pre-transposed) -> same contiguous pattern.
// D: col=lane&15, row=(lane>>4)*4+reg  [m89-verified].

template <bool RELU, bool FP32OUT>
__global__ __launch_bounds__(256, 2) void gemm_mfma(const ushort* __restrict__ hbin,
                                                    const ushort* __restrict__ neighb,
                                                    const ushort* __restrict__ Wt,
                                                    const float* __restrict__ bias,
                                                    float* __restrict__ out32,
                                                    ushort* __restrict__ outbf) {
    __shared__ ushort As[128 * 40];
    __shared__ ushort Bs[128 * 40];
    const int tid = threadIdx.x;
    const int lane = tid & 63;
    const int w = tid >> 6;
    const int wrow = w >> 1, wcol = w & 1;
    const int nbase = blockIdx.x * 128;
    const int l15 = lane & 15, l4 = lane >> 4;

    float4v acc[4][4];
#pragma unroll
    for (int i = 0; i < 4; i++)
#pragma unroll
        for (int j = 0; j < 4; j++) acc[i][j] = (float4v)0.f;

    for (int ks = 0; ks < 8; ++ks) {
        const int k0 = ks * 32;
        const ushort* Xsrc = (ks < 4) ? hbin : neighb;
        const int kk = k0 & 127;
        if (ks) __syncthreads();  // protect previous iter's LDS reads
        // stage A: 128 rows x 32 k bf16 = 512 x 16B chunks, 2 per thread
#pragma unroll
        for (int j = 0; j < 2; j++) {
            int ch = tid + j * 256;
            int r = ch >> 2, cp = ch & 3;
            int gn = nbase + r;
            if (gn > N_NODES - 1) gn = N_NODES - 1;
            *(uint4*)&As[r * 40 + cp * 8] =
                *(const uint4*)&Xsrc[(size_t)gn * 128 + kk + cp * 8];
        }
        // stage B: 128 cols x 32 k bf16 from Wt[col][256]
#pragma unroll
        for (int j = 0; j < 2; j++) {
            int ch = tid + j * 256;
            int r = ch >> 2, cp = ch & 3;
            *(uint4*)&Bs[r * 40 + cp * 8] =
                *(const uint4*)&Wt[(size_t)r * 256 + k0 + cp * 8];
        }
        __syncthreads();
        short8v a[4], b[4];
#pragma unroll
        for (int i = 0; i < 4; i++)
            a[i] = *(const short8v*)&As[(wrow * 64 + i * 16 + l15) * 40 + l4 * 8];
#pragma unroll
        for (int j = 0; j < 4; j++)
            b[j] = *(const short8v*)&Bs[(wcol * 64 + j * 16 + l15) * 40 + l4 * 8];
#pragma unroll
        for (int i = 0; i < 4; i++)
#pragma unroll
            for (int j = 0; j < 4; j++)
                acc[i][j] = __builtin_amdgcn_mfma_f32_16x16x32_bf16(
                    a[i], b[j], acc[i][j], 0, 0, 0);
    }

    // epilogue: D frag (i,j): row = nbase+wrow*64+i*16+l4*4+reg, col = wcol*64+j*16+l15
#pragma unroll
    for (int j = 0; j < 4; j++) {
        int col = wcol * 64 + j * 16 + l15;
        float bv = bias[col];
#pragma unroll
        for (int i = 0; i < 4; i++) {
            int row0 = nbase + wrow * 64 + i * 16 + l4 * 4;
#pragma unroll
            for (int r = 0; r < 4; r++) {
                int row = row0 + r;
                if (row < N_NODES) {
                    float v = acc[i][j][r] + bv;
                    if (RELU) v = fmaxf(v, 0.f);
                    if (FP32OUT) {
                        out32[(size_t)row * 128 + col] = v;
                    } else {
                        outbf[(size_t)row * 128 + col] = bf16rne(v);
                    }
                }
            }
        }
    }
}

// ---------------- launch ----------------

extern "C" void kernel_launch(void* const* d_in, const int* in_sizes, int n_in,
                              void* d_out, int out_size, void* d_ws, size_t ws_size,
                              hipStream_t stream) {
    const float* feats = (const float*)d_in[0];
    const int* src = (const int*)d_in[1];
    const int* dst = (const int*)d_in[2];
    const float* wS[3] = {(const float*)d_in[3], (const float*)d_in[6], (const float*)d_in[9]};
    const float* wN[3] = {(const float*)d_in[4], (const float*)d_in[7], (const float*)d_in[10]};
    const float* bb[3] = {(const float*)d_in[5], (const float*)d_in[8], (const float*)d_in[11]};
    float* out = (float*)d_out;

    char* p = (char*)d_ws;
    auto alloc = [&](size_t bytes) {
        char* r = p;
        p += (bytes + 255) & ~(size_t)255;
        return r;
    };
    ushort* hbA = (ushort*)alloc((size_t)N_NODES * DF * sizeof(ushort));    // 12.8 MB
    ushort* hbB = (ushort*)alloc((size_t)N_NODES * DF * sizeof(ushort));    // 12.8 MB
    ushort* neighb = (ushort*)alloc((size_t)N_NODES * DF * sizeof(ushort)); // 12.8 MB
    ushort* Wt = (ushort*)alloc((size_t)3 * 128 * 256 * sizeof(ushort));    // 192 KB
    int* deg_c = (int*)alloc((size_t)NC * N_NODES * sizeof(int));
    int* cstart = (int*)alloc((size_t)NC * N_NODES * sizeof(int));
    int* deg = (int*)alloc((size_t)N_NODES * sizeof(int));
    int* rstart = (int*)alloc((size_t)N_NODES * sizeof(int));
    int* counter = (int*)alloc(sizeof(int));
    int* loc = (int*)alloc((size_t)N_EDGES * sizeof(int));
    int* adj = (int*)alloc((size_t)(N_EDGES + 4 * N_NODES) * sizeof(int));

    const int EB = (N_EDGES + 255) / 256;
    const int NB = (N_NODES + 255) / 256;
    const int CB = (N_NODES * DF / 4 + 255) / 256;
    const int WB = (128 * 256 + 255) / 256;

    // CSR build (reused by all 3 layers)
    hipMemsetAsync(deg_c, 0, (size_t)NC * N_NODES * sizeof(int), stream);
    hipMemsetAsync(counter, 0, sizeof(int), stream);
    p1_kernel<<<EB, 256, 0, stream>>>(dst, deg_c, loc);
    alloc_kernel<<<NB, 256, 0, stream>>>(deg_c, deg, rstart, cstart, counter);
    p2_kernel<<<EB, 256, 0, stream>>>(src, dst, loc, cstart, adj);

    // weight prep + input conversion
    wprep_kernel<<<WB, 256, 0, stream>>>(wS[0], wN[0], Wt);
    wprep_kernel<<<WB, 256, 0, stream>>>(wS[1], wN[1], Wt + 128 * 256);
    wprep_kernel<<<WB, 256, 0, stream>>>(wS[2], wN[2], Wt + 2 * 128 * 256);
    conv_kernel<<<CB, 256, 0, stream>>>(feats, hbA);

    const int AGG_GRID = (N_NODES + 3) / 4;
    const int GB = (N_NODES + 127) / 128;

    // layer 0: hbA -> hbB
    agg_kernel<<<AGG_GRID, 256, 0, stream>>>(hbA, rstart, deg, adj, neighb);
    gemm_mfma<true, false><<<GB, 256, 0, stream>>>(hbA, neighb, Wt, bb[0], nullptr, hbB);
    // layer 1: hbB -> hbA
    agg_kernel<<<AGG_GRID, 256, 0, stream>>>(hbB, rstart, deg, adj, neighb);
    gemm_mfma<true, false><<<GB, 256, 0, stream>>>(hbB, neighb, Wt + 128 * 256, bb[1], nullptr, hbA);
    // layer 2: hbA -> d_out (fp32)
    agg_kernel<<<AGG_GRID, 256, 0, stream>>>(hbA, rstart, deg, adj, neighb);
    gemm_mfma<false, true><<<GB, 256, 0, stream>>>(hbA, neighb, Wt + 2 * 128 * 256, bb[2], out, nullptr);
}

// Round 9
// 371.337 us; speedup vs baseline: 2.2539x; 1.1714x over previous
//
#include <hip/hip_runtime.h>
#include <hip/hip_bf16.h>

#define N_NODES 50000
#define N_EDGES 1600000
#define DF 128
#define EPB 2500          // edges per partition block
#define B1 640            // partition blocks (EPB*B1 == N_EDGES)
#define NBIN 196          // ceil(50000/256)

typedef __attribute__((ext_vector_type(8))) short short8v;
typedef __attribute__((ext_vector_type(4))) float float4v;

__device__ __forceinline__ ushort bf16rne(float f) {
    uint u = __float_as_uint(f);
    return (ushort)((u + 0x7fffu + ((u >> 16) & 1u)) >> 16);
}

// ---------------- CSR build: two-level partition, no global atomics ----------------

// Kernel 1: per-block histogram of dst>>8 -> gh[d][blk]
__global__ __launch_bounds__(256) void h1_kernel(const int* __restrict__ dst,
                                                 int* __restrict__ gh) {
    __shared__ int hist[NBIN];
    const int tid = threadIdx.x;
    const int blk = blockIdx.x;
    if (tid < NBIN) hist[tid] = 0;
    __syncthreads();
    const int lo = blk * EPB, hiE = min(lo + EPB, N_EDGES);
    for (int i = lo + tid; i < hiE; i += 256) atomicAdd(&hist[dst[i] >> 8], 1);
    __syncthreads();
    if (tid < NBIN) gh[tid * B1 + blk] = hist[tid];
}

// Kernel 2: per-digit-row exclusive scan of gh (in place), row total -> rowtot[d]
__global__ __launch_bounds__(256) void scanA_kernel(int* __restrict__ gh,
                                                    int* __restrict__ rowtot) {
    __shared__ int buf[256];
    __shared__ int carry_s;
    const int tid = threadIdx.x;
    const int d = blockIdx.x;
    if (tid == 0) carry_s = 0;
    __syncthreads();
    for (int base = 0; base < B1; base += 256) {
        int idx = base + tid;
        int v = (idx < B1) ? gh[d * B1 + idx] : 0;
        buf[tid] = v;
        __syncthreads();
#pragma unroll
        for (int off = 1; off < 256; off <<= 1) {
            int t = (tid >= off) ? buf[tid - off] : 0;
            __syncthreads();
            buf[tid] += t;
            __syncthreads();
        }
        int carry = carry_s;
        if (idx < B1) gh[d * B1 + idx] = carry + buf[tid] - v;
        int tot = buf[255];
        __syncthreads();
        if (tid == 0) carry_s = carry + tot;
        __syncthreads();
    }
    if (tid == 0) rowtot[d] = carry_s;
}

// Kernel 3: exclusive scan of rowtot -> rowbase[0..NBIN], rowbase[NBIN]=E
__global__ __launch_bounds__(256) void scanB_kernel(const int* __restrict__ rowtot,
                                                    int* __restrict__ rowbase) {
    __shared__ int buf[256];
    const int tid = threadIdx.x;
    int v = (tid < NBIN) ? rowtot[tid] : 0;
    buf[tid] = v;
    __syncthreads();
#pragma unroll
    for (int off = 1; off < 256; off <<= 1) {
        int t = (tid >= off) ? buf[tid - off] : 0;
        __syncthreads();
        buf[tid] += t;
        __syncthreads();
    }
    if (tid < NBIN) rowbase[tid] = buf[tid] - v;
    if (tid == 0) rowbase[NBIN] = buf[255];
}

// Kernel 4: partition edges into bins (LDS cursors), pack (src,dst) 8B
__global__ __launch_bounds__(256) void scatter1_kernel(const int* __restrict__ src,
                                                       const int* __restrict__ dst,
                                                       const int* __restrict__ gh,
                                                       const int* __restrict__ rowbase,
                                                       uint2* __restrict__ tmp) {
    __shared__ int cur[NBIN];
    const int tid = threadIdx.x;
    const int blk = blockIdx.x;
    if (tid < NBIN) cur[tid] = rowbase[tid] + gh[tid * B1 + blk];
    __syncthreads();
    const int lo = blk * EPB, hiE = min(lo + EPB, N_EDGES);
    for (int i = lo + tid; i < hiE; i += 256) {
        int d = dst[i];
        int pos = atomicAdd(&cur[d >> 8], 1);
        uint2 v;
        v.x = (uint)src[i];
        v.y = (uint)d;
        tmp[pos] = v;
    }
}

// Kernel 5: one block per bin: low-digit histogram, padded scan + bump alloc,
// final scatter of src into adj; writes deg/rstart (rstart 4-aligned).
__global__ __launch_bounds__(256) void pass2_kernel(const uint2* __restrict__ tmp,
                                                    const int* __restrict__ rowbase,
                                                    int* __restrict__ deg,
                                                    int* __restrict__ rstart,
                                                    int* __restrict__ adj,
                                                    int* __restrict__ counter) {
    __shared__ int hist[256];
    __shared__ int sbuf[256];
    __shared__ int cur2[256];
    __shared__ int base_s;
    const int tid = threadIdx.x;
    const int hi = blockIdx.x;
    const int s = rowbase[hi], e = rowbase[hi + 1];
    hist[tid] = 0;
    __syncthreads();
    for (int i = s + tid; i < e; i += 256) atomicAdd(&hist[tmp[i].y & 255u], 1);
    __syncthreads();
    int h = hist[tid];
    int v = (h + 3) & ~3;  // padded region size
    sbuf[tid] = v;
    __syncthreads();
#pragma unroll
    for (int off = 1; off < 256; off <<= 1) {
        int t = (tid >= off) ? sbuf[tid - off] : 0;
        __syncthreads();
        sbuf[tid] += t;
        __syncthreads();
    }
    if (tid == 255) base_s = atomicAdd(counter, sbuf[255]);
    __syncthreads();
    int rs = base_s + sbuf[tid] - v;
    int n = hi * 256 + tid;
    if (n < N_NODES) {
        deg[n] = h;
        rstart[n] = rs;
    }
    cur2[tid] = rs;
    __syncthreads();
    for (int i = s + tid; i < e; i += 256) {
        uint2 t2 = tmp[i];
        int pos = atomicAdd(&cur2[t2.y & 255u], 1);
        adj[pos] = (int)t2.x;
    }
}

// ---------------- fp32 -> bf16 conversion (RNE), 4 elems/thread ----------------

__global__ __launch_bounds__(256) void conv_kernel(const float* __restrict__ h,
                                                   ushort* __restrict__ hb) {
    int i = blockIdx.x * 256 + threadIdx.x;
    const int total = N_NODES * DF / 4;
    if (i < total) {
        float4 v = ((const float4*)h)[i];
        ushort4 o;
        o.x = bf16rne(v.x); o.y = bf16rne(v.y);
        o.z = bf16rne(v.z); o.w = bf16rne(v.w);
        ((ushort4*)hb)[i] = o;
    }
}

// ---------------- weight prep: Wt[col][k] bf16, k = [Ws rows | Wn rows] ----------

__global__ __launch_bounds__(256) void wprep_kernel(const float* __restrict__ wS,
                                                    const float* __restrict__ wN,
                                                    ushort* __restrict__ Wt) {
    int idx = blockIdx.x * 256 + threadIdx.x;  // 128*256 total
    if (idx < 128 * 256) {
        int c = idx >> 8;
        int k = idx & 255;
        float v = (k < 128) ? wS[k * 128 + c] : wN[(k - 128) * 128 + c];
        Wt[c * 256 + k] = bf16rne(v);
    }
}

// ---------------- aggregation: one wave per node, 8 rows in flight, bf16 -> bf16 --

__global__ __launch_bounds__(256) void agg_kernel(const ushort* __restrict__ hb,
                                                  const int* __restrict__ rstart,
                                                  const int* __restrict__ degv,
                                                  const int* __restrict__ adj,
                                                  ushort* __restrict__ neighb) {
    const int wave = threadIdx.x >> 6;
    const int lane = threadIdx.x & 63;
    const int n = blockIdx.x * 4 + wave;
    if (n >= N_NODES) return;
    const int s = rstart[n];   // multiple of 4 -> 16B-aligned int4 reads
    const int d = degv[n];
    const int off = lane * 2;
    float ax[8], ay[8];
#pragma unroll
    for (int j = 0; j < 8; j++) { ax[j] = 0.f; ay[j] = 0.f; }
    int i = 0;
    for (; i + 8 <= d; i += 8) {
        int4 a0 = *(const int4*)&adj[s + i];
        int4 a1 = *(const int4*)&adj[s + i + 4];
        uint u0 = *(const uint*)&hb[(size_t)a0.x * DF + off];
        uint u1 = *(const uint*)&hb[(size_t)a0.y * DF + off];
        uint u2 = *(const uint*)&hb[(size_t)a0.z * DF + off];
        uint u3 = *(const uint*)&hb[(size_t)a0.w * DF + off];
        uint u4 = *(const uint*)&hb[(size_t)a1.x * DF + off];
        uint u5 = *(const uint*)&hb[(size_t)a1.y * DF + off];
        uint u6 = *(const uint*)&hb[(size_t)a1.z * DF + off];
        uint u7 = *(const uint*)&hb[(size_t)a1.w * DF + off];
        ax[0] += __uint_as_float(u0 << 16); ay[0] += __uint_as_float(u0 & 0xffff0000u);
        ax[1] += __uint_as_float(u1 << 16); ay[1] += __uint_as_float(u1 & 0xffff0000u);
        ax[2] += __uint_as_float(u2 << 16); ay[2] += __uint_as_float(u2 & 0xffff0000u);
        ax[3] += __uint_as_float(u3 << 16); ay[3] += __uint_as_float(u3 & 0xffff0000u);
        ax[4] += __uint_as_float(u4 << 16); ay[4] += __uint_as_float(u4 & 0xffff0000u);
        ax[5] += __uint_as_float(u5 << 16); ay[5] += __uint_as_float(u5 & 0xffff0000u);
        ax[6] += __uint_as_float(u6 << 16); ay[6] += __uint_as_float(u6 & 0xffff0000u);
        ax[7] += __uint_as_float(u7 << 16); ay[7] += __uint_as_float(u7 & 0xffff0000u);
    }
    for (; i < d; i++) {
        int s0 = adj[s + i];
        uint u = *(const uint*)&hb[(size_t)s0 * DF + off];
        ax[0] += __uint_as_float(u << 16);
        ay[0] += __uint_as_float(u & 0xffff0000u);
    }
    float sx = (ax[0] + ax[1]) + (ax[2] + ax[3]) + ((ax[4] + ax[5]) + (ax[6] + ax[7]));
    float sy = (ay[0] + ay[1]) + (ay[2] + ay[3]) + ((ay[4] + ay[5]) + (ay[6] + ay[7]));
    float inv = 1.0f / (float)(d < 1 ? 1 : d);
    ushort2 o;
    o.x = bf16rne(sx * inv);
    o.y = bf16rne(sy * inv);
    *(ushort2*)&neighb[(size_t)n * DF + off] = o;
}

// ---------------- MFMA GEMM: out = act([hb | neighb] @ Wt^T + b) -----------------

template <bool RELU, bool FP32OUT>
__global__ __launch_bounds__(256, 2) void gemm_mfma(const ushort* __restrict__ hbin,
                                                    const ushort* __restrict__ neighb,
                                                    const ushort* __restrict__ Wt,
                                                    const float* __restrict__ bias,
                                                    float* __restrict__ out32,
                                                    ushort* __restrict__ outbf) {
    __shared__ ushort As[128 * 40];
    __shared__ ushort Bs[128 * 40];
    const int tid = threadIdx.x;
    const int lane = tid & 63;
    const int w = tid >> 6;
    const int wrow = w >> 1, wcol = w & 1;
    const int nbase = blockIdx.x * 128;
    const int l15 = lane & 15, l4 = lane >> 4;

    float4v acc[4][4];
#pragma unroll
    for (int i = 0; i < 4; i++)
#pragma unroll
        for (int j = 0; j < 4; j++) acc[i][j] = (float4v)0.f;

    for (int ks = 0; ks < 8; ++ks) {
        const int k0 = ks * 32;
        const ushort* Xsrc = (ks < 4) ? hbin : neighb;
        const int kk = k0 & 127;
        if (ks) __syncthreads();
#pragma unroll
        for (int j = 0; j < 2; j++) {
            int ch = tid + j * 256;
            int r = ch >> 2, cp = ch & 3;
            int gn = nbase + r;
            if (gn > N_NODES - 1) gn = N_NODES - 1;
            *(uint4*)&As[r * 40 + cp * 8] =
                *(const uint4*)&Xsrc[(size_t)gn * 128 + kk + cp * 8];
        }
#pragma unroll
        for (int j = 0; j < 2; j++) {
            int ch = tid + j * 256;
            int r = ch >> 2, cp = ch & 3;
            *(uint4*)&Bs[r * 40 + cp * 8] =
                *(const uint4*)&Wt[(size_t)r * 256 + k0 + cp * 8];
        }
        __syncthreads();
        short8v a[4], b[4];
#pragma unroll
        for (int i = 0; i < 4; i++)
            a[i] = *(const short8v*)&As[(wrow * 64 + i * 16 + l15) * 40 + l4 * 8];
#pragma unroll
        for (int j = 0; j < 4; j++)
            b[j] = *(const short8v*)&Bs[(wcol * 64 + j * 16 + l15) * 40 + l4 * 8];
#pragma unroll
        for (int i = 0; i < 4; i++)
#pragma unroll
            for (int j = 0; j < 4; j++)
                acc[i][j] = __builtin_amdgcn_mfma_f32_16x16x32_bf16(
                    a[i], b[j], acc[i][j], 0, 0, 0);
    }

#pragma unroll
    for (int j = 0; j < 4; j++) {
        int col = wcol * 64 + j * 16 + l15;
        float bv = bias[col];
#pragma unroll
        for (int i = 0; i < 4; i++) {
            int row0 = nbase + wrow * 64 + i * 16 + l4 * 4;
#pragma unroll
            for (int r = 0; r < 4; r++) {
                int row = row0 + r;
                if (row < N_NODES) {
                    float v = acc[i][j][r] + bv;
                    if (RELU) v = fmaxf(v, 0.f);
                    if (FP32OUT) {
                        out32[(size_t)row * 128 + col] = v;
                    } else {
                        outbf[(size_t)row * 128 + col] = bf16rne(v);
                    }
                }
            }
        }
    }
}

// ---------------- launch ----------------

extern "C" void kernel_launch(void* const* d_in, const int* in_sizes, int n_in,
                              void* d_out, int out_size, void* d_ws, size_t ws_size,
                              hipStream_t stream) {
    const float* feats = (const float*)d_in[0];
    const int* src = (const int*)d_in[1];
    const int* dst = (const int*)d_in[2];
    const float* wS[3] = {(const float*)d_in[3], (const float*)d_in[6], (const float*)d_in[9]};
    const float* wN[3] = {(const float*)d_in[4], (const float*)d_in[7], (const float*)d_in[10]};
    const float* bb[3] = {(const float*)d_in[5], (const float*)d_in[8], (const float*)d_in[11]};
    float* out = (float*)d_out;

    char* p = (char*)d_ws;
    auto alloc = [&](size_t bytes) {
        char* r = p;
        p += (bytes + 255) & ~(size_t)255;
        return r;
    };
    ushort* hbA = (ushort*)alloc((size_t)N_NODES * DF * sizeof(ushort));    // 12.8 MB
    ushort* hbB = (ushort*)alloc((size_t)N_NODES * DF * sizeof(ushort));    // 12.8 MB
    ushort* neighb = (ushort*)alloc((size_t)N_NODES * DF * sizeof(ushort)); // 12.8 MB
    ushort* Wt = (ushort*)alloc((size_t)3 * 128 * 256 * sizeof(ushort));    // 192 KB
    uint2* tmp = (uint2*)alloc((size_t)N_EDGES * sizeof(uint2));            // 12.8 MB
    int* gh = (int*)alloc((size_t)NBIN * B1 * sizeof(int));                 // 500 KB
    int* rowtot = (int*)alloc((size_t)NBIN * sizeof(int));
    int* rowbase = (int*)alloc((size_t)(NBIN + 1) * sizeof(int));
    int* deg = (int*)alloc((size_t)N_NODES * sizeof(int));
    int* rstart = (int*)alloc((size_t)N_NODES * sizeof(int));
    int* counter = (int*)alloc(sizeof(int));
    int* adj = (int*)alloc((size_t)(N_EDGES + 4 * N_NODES) * sizeof(int));  // 7.2 MB

    const int CB = (N_NODES * DF / 4 + 255) / 256;
    const int WB = (128 * 256 + 255) / 256;

    // CSR build via two-level partition (no global atomics in the hot path)
    hipMemsetAsync(counter, 0, sizeof(int), stream);
    h1_kernel<<<B1, 256, 0, stream>>>(dst, gh);
    scanA_kernel<<<NBIN, 256, 0, stream>>>(gh, rowtot);
    scanB_kernel<<<1, 256, 0, stream>>>(rowtot, rowbase);
    scatter1_kernel<<<B1, 256, 0, stream>>>(src, dst, gh, rowbase, tmp);
    pass2_kernel<<<NBIN, 256, 0, stream>>>(tmp, rowbase, deg, rstart, adj, counter);

    // weight prep + input conversion
    wprep_kernel<<<WB, 256, 0, stream>>>(wS[0], wN[0], Wt);
    wprep_kernel<<<WB, 256, 0, stream>>>(wS[1], wN[1], Wt + 128 * 256);
    wprep_kernel<<<WB, 256, 0, stream>>>(wS[2], wN[2], Wt + 2 * 128 * 256);
    conv_kernel<<<CB, 256, 0, stream>>>(feats, hbA);

    const int AGG_GRID = (N_NODES + 3) / 4;
    const int GB = (N_NODES + 127) / 128;

    // layer 0: hbA -> hbB
    agg_kernel<<<AGG_GRID, 256, 0, stream>>>(hbA, rstart, deg, adj, neighb);
    gemm_mfma<true, false><<<GB, 256, 0, stream>>>(hbA, neighb, Wt, bb[0], nullptr, hbB);
    // layer 1: hbB -> hbA
    agg_kernel<<<AGG_GRID, 256, 0, stream>>>(hbB, rstart, deg, adj, neighb);
    gemm_mfma<true, false><<<GB, 256, 0, stream>>>(hbB, neighb, Wt + 128 * 256, bb[1], nullptr, hbA);
    // layer 2: hbA -> d_out (fp32)
    agg_kernel<<<AGG_GRID, 256, 0, stream>>>(hbA, rstart, deg, adj, neighb);
    gemm_mfma<false, true><<<GB, 256, 0, stream>>>(hbA, neighb, Wt + 2 * 128 * 256, bb[2], out, nullptr);
}

// Round 10
// 345.602 us; speedup vs baseline: 2.4217x; 1.0745x over previous
//
#include <hip/hip_runtime.h>
#include <hip/hip_bf16.h>

#define N_NODES 50000
#define N_EDGES 1600000
#define DF 128
#define EPB 2500          // edges per partition block
#define B1 640            // partition blocks (EPB*B1 == N_EDGES)
#define NBIN 196          // ceil(50000/256)

typedef __attribute__((ext_vector_type(8))) short short8v;
typedef __attribute__((ext_vector_type(4))) float float4v;

__device__ __forceinline__ ushort bf16rne(float f) {
    uint u = __float_as_uint(f);
    return (ushort)((u + 0x7fffu + ((u >> 16) & 1u)) >> 16);
}

// ---------------- CSR build: two-level partition, no global atomics ----------------

__global__ __launch_bounds__(256) void h1_kernel(const int* __restrict__ dst,
                                                 int* __restrict__ gh) {
    __shared__ int hist[NBIN];
    const int tid = threadIdx.x;
    const int blk = blockIdx.x;
    if (tid < NBIN) hist[tid] = 0;
    __syncthreads();
    const int lo = blk * EPB, hiE = min(lo + EPB, N_EDGES);
    for (int i = lo + tid; i < hiE; i += 256) atomicAdd(&hist[dst[i] >> 8], 1);
    __syncthreads();
    if (tid < NBIN) gh[tid * B1 + blk] = hist[tid];
}

__global__ __launch_bounds__(256) void scanA_kernel(int* __restrict__ gh,
                                                    int* __restrict__ rowtot) {
    __shared__ int buf[256];
    __shared__ int carry_s;
    const int tid = threadIdx.x;
    const int d = blockIdx.x;
    if (tid == 0) carry_s = 0;
    __syncthreads();
    for (int base = 0; base < B1; base += 256) {
        int idx = base + tid;
        int v = (idx < B1) ? gh[d * B1 + idx] : 0;
        buf[tid] = v;
        __syncthreads();
#pragma unroll
        for (int off = 1; off < 256; off <<= 1) {
            int t = (tid >= off) ? buf[tid - off] : 0;
            __syncthreads();
            buf[tid] += t;
            __syncthreads();
        }
        int carry = carry_s;
        if (idx < B1) gh[d * B1 + idx] = carry + buf[tid] - v;
        int tot = buf[255];
        __syncthreads();
        if (tid == 0) carry_s = carry + tot;
        __syncthreads();
    }
    if (tid == 0) rowtot[d] = carry_s;
}

__global__ __launch_bounds__(256) void scanB_kernel(const int* __restrict__ rowtot,
                                                    int* __restrict__ rowbase) {
    __shared__ int buf[256];
    const int tid = threadIdx.x;
    int v = (tid < NBIN) ? rowtot[tid] : 0;
    buf[tid] = v;
    __syncthreads();
#pragma unroll
    for (int off = 1; off < 256; off <<= 1) {
        int t = (tid >= off) ? buf[tid - off] : 0;
        __syncthreads();
        buf[tid] += t;
        __syncthreads();
    }
    if (tid < NBIN) rowbase[tid] = buf[tid] - v;
    if (tid == 0) rowbase[NBIN] = buf[255];
}

__global__ __launch_bounds__(256) void scatter1_kernel(const int* __restrict__ src,
                                                       const int* __restrict__ dst,
                                                       const int* __restrict__ gh,
                                                       const int* __restrict__ rowbase,
                                                       uint2* __restrict__ tmp) {
    __shared__ int cur[NBIN];
    const int tid = threadIdx.x;
    const int blk = blockIdx.x;
    if (tid < NBIN) cur[tid] = rowbase[tid] + gh[tid * B1 + blk];
    __syncthreads();
    const int lo = blk * EPB, hiE = min(lo + EPB, N_EDGES);
    for (int i = lo + tid; i < hiE; i += 256) {
        int d = dst[i];
        int pos = atomicAdd(&cur[d >> 8], 1);
        uint2 v;
        v.x = (uint)src[i];
        v.y = (uint)d;
        tmp[pos] = v;
    }
}

__global__ __launch_bounds__(256) void pass2_kernel(const uint2* __restrict__ tmp,
                                                    const int* __restrict__ rowbase,
                                                    int* __restrict__ deg,
                                                    int* __restrict__ rstart,
                                                    int* __restrict__ adj,
                                                    int* __restrict__ counter) {
    __shared__ int hist[256];
    __shared__ int sbuf[256];
    __shared__ int cur2[256];
    __shared__ int base_s;
    const int tid = threadIdx.x;
    const int hi = blockIdx.x;
    const int s = rowbase[hi], e = rowbase[hi + 1];
    hist[tid] = 0;
    __syncthreads();
    for (int i = s + tid; i < e; i += 256) atomicAdd(&hist[tmp[i].y & 255u], 1);
    __syncthreads();
    int h = hist[tid];
    int v = (h + 3) & ~3;
    sbuf[tid] = v;
    __syncthreads();
#pragma unroll
    for (int off = 1; off < 256; off <<= 1) {
        int t = (tid >= off) ? sbuf[tid - off] : 0;
        __syncthreads();
        sbuf[tid] += t;
        __syncthreads();
    }
    if (tid == 255) base_s = atomicAdd(counter, sbuf[255]);
    __syncthreads();
    int rs = base_s + sbuf[tid] - v;
    int n = hi * 256 + tid;
    if (n < N_NODES) {
        deg[n] = h;
        rstart[n] = rs;
    }
    cur2[tid] = rs;
    __syncthreads();
    for (int i = s + tid; i < e; i += 256) {
        uint2 t2 = tmp[i];
        int pos = atomicAdd(&cur2[t2.y & 255u], 1);
        adj[pos] = (int)t2.x;
    }
}

// ---------------- fp32 -> bf16 conversion (RNE), 4 elems/thread ----------------

__global__ __launch_bounds__(256) void conv_kernel(const float* __restrict__ h,
                                                   ushort* __restrict__ hb) {
    int i = blockIdx.x * 256 + threadIdx.x;
    const int total = N_NODES * DF / 4;
    if (i < total) {
        float4 v = ((const float4*)h)[i];
        ushort4 o;
        o.x = bf16rne(v.x); o.y = bf16rne(v.y);
        o.z = bf16rne(v.z); o.w = bf16rne(v.w);
        ((ushort4*)hb)[i] = o;
    }
}

// ---------------- weight prep: Wt[col][k] bf16, k = [Ws rows | Wn rows] ----------

__global__ __launch_bounds__(256) void wprep_kernel(const float* __restrict__ wS,
                                                    const float* __restrict__ wN,
                                                    ushort* __restrict__ Wt) {
    int idx = blockIdx.x * 256 + threadIdx.x;
    if (idx < 128 * 256) {
        int c = idx >> 8;
        int k = idx & 255;
        float v = (k < 128) ? wS[k * 128 + c] : wN[(k - 128) * 128 + c];
        Wt[c * 256 + k] = bf16rne(v);
    }
}

// ---------------- aggregation: 1 wave/node, quarter-wave per edge row ------------
// Each quarter (16 lanes x 16B) gathers one edge's full 256B bf16 row.
// 4 edges per gather instruction, 16-edge unroll = 4 gathers in flight.
// Cross-quarter reduce via shfl_xor(16/32); lanes 0-15 write 8 bf16 each.

__global__ __launch_bounds__(256) void agg_kernel(const ushort* __restrict__ hb,
                                                  const int* __restrict__ rstart,
                                                  const int* __restrict__ degv,
                                                  const int* __restrict__ adj,
                                                  ushort* __restrict__ neighb) {
    const int wave = threadIdx.x >> 6;
    const int lane = threadIdx.x & 63;
    const int n = blockIdx.x * 4 + wave;
    if (n >= N_NODES) return;
    const int s = rstart[n];
    const int d = degv[n];
    const int q = lane >> 4;       // quarter: which of 4 concurrent edges
    const int f = lane & 15;       // 8-dim group within row
    const size_t foff = (size_t)(f * 8);

    float acc[8];
#pragma unroll
    for (int j = 0; j < 8; j++) acc[j] = 0.f;

#define GATHER_ADD(EIDX)                                                    \
    {                                                                       \
        int e_ = adj[(EIDX)];                                               \
        uint4 u_ = *(const uint4*)&hb[(size_t)e_ * DF + foff];              \
        acc[0] += __uint_as_float(u_.x << 16);                              \
        acc[1] += __uint_as_float(u_.x & 0xffff0000u);                      \
        acc[2] += __uint_as_float(u_.y << 16);                              \
        acc[3] += __uint_as_float(u_.y & 0xffff0000u);                      \
        acc[4] += __uint_as_float(u_.z << 16);                              \
        acc[5] += __uint_as_float(u_.z & 0xffff0000u);                      \
        acc[6] += __uint_as_float(u_.w << 16);                              \
        acc[7] += __uint_as_float(u_.w & 0xffff0000u);                      \
    }

    int i = 0;
    for (; i + 16 <= d; i += 16) {
        GATHER_ADD(s + i + q)
        GATHER_ADD(s + i + 4 + q)
        GATHER_ADD(s + i + 8 + q)
        GATHER_ADD(s + i + 12 + q)
    }
    for (; i + 4 <= d; i += 4) {
        GATHER_ADD(s + i + q)
    }
    if (i < d) {
        int r = d - i;  // 1..3
        if (q < r) GATHER_ADD(s + i + q)
    }
#undef GATHER_ADD

    // cross-quarter reduction: sum the 4 quarters' accumulators (same dims)
#pragma unroll
    for (int j = 0; j < 8; j++) {
        acc[j] += __shfl_xor(acc[j], 16, 64);
        acc[j] += __shfl_xor(acc[j], 32, 64);
    }

    if (q == 0) {
        float inv = 1.0f / (float)(d < 1 ? 1 : d);
        uint4 o;
        o.x = (uint)bf16rne(acc[0] * inv) | ((uint)bf16rne(acc[1] * inv) << 16);
        o.y = (uint)bf16rne(acc[2] * inv) | ((uint)bf16rne(acc[3] * inv) << 16);
        o.z = (uint)bf16rne(acc[4] * inv) | ((uint)bf16rne(acc[5] * inv) << 16);
        o.w = (uint)bf16rne(acc[6] * inv) | ((uint)bf16rne(acc[7] * inv) << 16);
        *(uint4*)&neighb[(size_t)n * DF + foff] = o;
    }
}

// ---------------- MFMA GEMM: out = act([hb | neighb] @ Wt^T + b) -----------------
// 64 nodes x 128 cols per block (782 blocks -> ~3/CU), 4 waves, each 64x32
// via 4x2 16x16x32 fragments. A [64][40], B [128][40] LDS bf16.

template <bool RELU, bool FP32OUT>
__global__ __launch_bounds__(256, 2) void gemm_mfma(const ushort* __restrict__ hbin,
                                                    const ushort* __restrict__ neighb,
                                                    const ushort* __restrict__ Wt,
                                                    const float* __restrict__ bias,
                                                    float* __restrict__ out32,
                                                    ushort* __restrict__ outbf) {
    __shared__ ushort As[64 * 40];
    __shared__ ushort Bs[128 * 40];
    const int tid = threadIdx.x;
    const int lane = tid & 63;
    const int w = tid >> 6;          // wave: cols w*32..w*32+31
    const int nbase = blockIdx.x * 64;
    const int l15 = lane & 15, l4 = lane >> 4;

    float4v acc[4][2];
#pragma unroll
    for (int i = 0; i < 4; i++)
#pragma unroll
        for (int j = 0; j < 2; j++) acc[i][j] = (float4v)0.f;

    for (int ks = 0; ks < 8; ++ks) {
        const int k0 = ks * 32;
        const ushort* Xsrc = (ks < 4) ? hbin : neighb;
        const int kk = k0 & 127;
        if (ks) __syncthreads();
        // stage A: 64 rows x 32 k = 256 x 16B chunks, 1 per thread
        {
            int r = tid >> 2, cp = tid & 3;
            int gn = nbase + r;
            if (gn > N_NODES - 1) gn = N_NODES - 1;
            *(uint4*)&As[r * 40 + cp * 8] =
                *(const uint4*)&Xsrc[(size_t)gn * 128 + kk + cp * 8];
        }
        // stage B: 128 cols x 32 k = 512 chunks, 2 per thread
#pragma unroll
        for (int j = 0; j < 2; j++) {
            int ch = tid + j * 256;
            int r = ch >> 2, cp = ch & 3;
            *(uint4*)&Bs[r * 40 + cp * 8] =
                *(const uint4*)&Wt[(size_t)r * 256 + k0 + cp * 8];
        }
        __syncthreads();
        short8v a[4], b[2];
#pragma unroll
        for (int i = 0; i < 4; i++)
            a[i] = *(const short8v*)&As[(i * 16 + l15) * 40 + l4 * 8];
#pragma unroll
        for (int j = 0; j < 2; j++)
            b[j] = *(const short8v*)&Bs[(w * 32 + j * 16 + l15) * 40 + l4 * 8];
#pragma unroll
        for (int i = 0; i < 4; i++)
#pragma unroll
            for (int j = 0; j < 2; j++)
                acc[i][j] = __builtin_amdgcn_mfma_f32_16x16x32_bf16(
                    a[i], b[j], acc[i][j], 0, 0, 0);
    }

#pragma unroll
    for (int j = 0; j < 2; j++) {
        int col = w * 32 + j * 16 + l15;
        float bv = bias[col];
#pragma unroll
        for (int i = 0; i < 4; i++) {
            int row0 = nbase + i * 16 + l4 * 4;
#pragma unroll
            for (int r = 0; r < 4; r++) {
                int row = row0 + r;
                if (row < N_NODES) {
                    float v = acc[i][j][r] + bv;
                    if (RELU) v = fmaxf(v, 0.f);
                    if (FP32OUT) {
                        out32[(size_t)row * 128 + col] = v;
                    } else {
                        outbf[(size_t)row * 128 + col] = bf16rne(v);
                    }
                }
            }
        }
    }
}

// ---------------- launch ----------------

extern "C" void kernel_launch(void* const* d_in, const int* in_sizes, int n_in,
                              void* d_out, int out_size, void* d_ws, size_t ws_size,
                              hipStream_t stream) {
    const float* feats = (const float*)d_in[0];
    const int* src = (const int*)d_in[1];
    const int* dst = (const int*)d_in[2];
    const float* wS[3] = {(const float*)d_in[3], (const float*)d_in[6], (const float*)d_in[9]};
    const float* wN[3] = {(const float*)d_in[4], (const float*)d_in[7], (const float*)d_in[10]};
    const float* bb[3] = {(const float*)d_in[5], (const float*)d_in[8], (const float*)d_in[11]};
    float* out = (float*)d_out;

    char* p = (char*)d_ws;
    auto alloc = [&](size_t bytes) {
        char* r = p;
        p += (bytes + 255) & ~(size_t)255;
        return r;
    };
    ushort* hbA = (ushort*)alloc((size_t)N_NODES * DF * sizeof(ushort));    // 12.8 MB
    ushort* hbB = (ushort*)alloc((size_t)N_NODES * DF * sizeof(ushort));    // 12.8 MB
    ushort* neighb = (ushort*)alloc((size_t)N_NODES * DF * sizeof(ushort)); // 12.8 MB
    ushort* Wt = (ushort*)alloc((size_t)3 * 128 * 256 * sizeof(ushort));    // 192 KB
    uint2* tmp = (uint2*)alloc((size_t)N_EDGES * sizeof(uint2));            // 12.8 MB
    int* gh = (int*)alloc((size_t)NBIN * B1 * sizeof(int));                 // 500 KB
    int* rowtot = (int*)alloc((size_t)NBIN * sizeof(int));
    int* rowbase = (int*)alloc((size_t)(NBIN + 1) * sizeof(int));
    int* deg = (int*)alloc((size_t)N_NODES * sizeof(int));
    int* rstart = (int*)alloc((size_t)N_NODES * sizeof(int));
    int* counter = (int*)alloc(sizeof(int));
    int* adj = (int*)alloc((size_t)(N_EDGES + 4 * N_NODES) * sizeof(int));  // 7.2 MB

    const int CB = (N_NODES * DF / 4 + 255) / 256;
    const int WB = (128 * 256 + 255) / 256;

    // CSR build via two-level partition (no global atomics in the hot path)
    hipMemsetAsync(counter, 0, sizeof(int), stream);
    h1_kernel<<<B1, 256, 0, stream>>>(dst, gh);
    scanA_kernel<<<NBIN, 256, 0, stream>>>(gh, rowtot);
    scanB_kernel<<<1, 256, 0, stream>>>(rowtot, rowbase);
    scatter1_kernel<<<B1, 256, 0, stream>>>(src, dst, gh, rowbase, tmp);
    pass2_kernel<<<NBIN, 256, 0, stream>>>(tmp, rowbase, deg, rstart, adj, counter);

    // weight prep + input conversion
    wprep_kernel<<<WB, 256, 0, stream>>>(wS[0], wN[0], Wt);
    wprep_kernel<<<WB, 256, 0, stream>>>(wS[1], wN[1], Wt + 128 * 256);
    wprep_kernel<<<WB, 256, 0, stream>>>(wS[2], wN[2], Wt + 2 * 128 * 256);
    conv_kernel<<<CB, 256, 0, stream>>>(feats, hbA);

    const int AGG_GRID = (N_NODES + 3) / 4;
    const int GB = (N_NODES + 63) / 64;

    // layer 0: hbA -> hbB
    agg_kernel<<<AGG_GRID, 256, 0, stream>>>(hbA, rstart, deg, adj, neighb);
    gemm_mfma<true, false><<<GB, 256, 0, stream>>>(hbA, neighb, Wt, bb[0], nullptr, hbB);
    // layer 1: hbB -> hbA
    agg_kernel<<<AGG_GRID, 256, 0, stream>>>(hbB, rstart, deg, adj, neighb);
    gemm_mfma<true, false><<<GB, 256, 0, stream>>>(hbB, neighb, Wt + 128 * 256, bb[1], nullptr, hbA);
    // layer 2: hbA -> d_out (fp32)
    agg_kernel<<<AGG_GRID, 256, 0, stream>>>(hbA, rstart, deg, adj, neighb);
    gemm_mfma<false, true><<<GB, 256, 0, stream>>>(hbA, neighb, Wt + 2 * 128 * 256, bb[2], out, nullptr);
}